// Round 9
// baseline (1569.034 us; speedup 1.0000x reference)
//
#include <hip/hip_runtime.h>
#include <hip/hip_fp16.h>

// MLPProjectionFilter round 9 = round-8 (deterministic, validated) with k2 at
// block=1024 (16 waves/CU vs 8): r8 counters showed k2 latency-bound at
// 1 WG/CU (Occupancy 19.6%, all pipes <13%). Same grid 256, same traffic,
// same dl layout/ws; fwd rbl = wave + 16*ri, transpose cb = wave (<12).
// Per iter: kP (per-tile: dl-sum, S/lambda, G=Mall*x-dlsum, rhs, Qinv MFMA,
// norms) then k2 (A-stream: v=Ax fwd + dl=A^T rs transpose, split-bf16 MFMA).

typedef short s16x8 __attribute__((ext_vector_type(8)));
typedef float f32x4 __attribute__((ext_vector_type(4)));
#define MFMA(a,b,c) __builtin_amdgcn_mfma_f32_16x16x32_bf16(a,b,c,0,0,0)

#define B2 2048
#define NV 192
#define NTT 222
#define KPAD 232
#define PR 328        // k2 rs LDS pitch (ushort), 320 rows/chunk + pad
#define PMX 200       // kP mxL pitch (f32)
#define NPART 48      // Gram partials

// ---- ws layout (float offsets) ----
#define O_S0  0u
#define O_S1  393216u
#define O_C0  786432u
#define O_C1  1179648u
#define O_U   1572864u     // __half[3*1200*2048] = 3,686,400 fl
#define O_DL  5259264u     // f32 [4][576][2048] = 4,718,592
#define O_SQP 9977856u     // f32 [4][2048][8] = 65,536
#define O_TOT 10043392u    // f32 [2048][2] = 4,096
#define O_XH  10047488u    // ushort[2048*192] = 196,608 fl
#define O_XL  10244096u
#define O_AH  10440704u    // ushort[3*80*6*512] = 368,640 fl each
#define O_AL  10809344u
#define O_ATH 11177984u
#define O_ATL 11546624u
#define O_QTH 11915264u    // ushort[12*7*512] = 21,504 fl
#define O_QTL 11936768u
#define O_MH  11958272u    // ushort[12*6*512] = 18,432 fl
#define O_ML2 11976704u
#define O_MP  11995136u    // f32 [48][192*192] Gram partials = 1,769,472
#define WS_FLOATS 13764608u  // 55.1 MB

__device__ inline unsigned short bh16(float v){
  union{float f; unsigned u;} a; a.f=v;
  return (unsigned short)((a.u + 0x7FFFu + ((a.u>>16)&1u))>>16);
}
__device__ inline void bsplit2(float v, unsigned short& h, unsigned short& l){
  h = bh16(v);
  union{unsigned u; float f;} hf; hf.u = ((unsigned)h)<<16;
  l = bh16(v - hf.f);
}

// Gram partials: MP[part][i*NV+j], part = mat*16 + rblk, rows [rblk*75, +75).
// Deterministic (no atomics), 3 independent FMA chains.
__global__ __launch_bounds__(256) void kM(const float* __restrict__ Av,
    const float* __restrict__ Aa, const float* __restrict__ Ap, float* __restrict__ MP) {
  int bb = blockIdx.x % 144, part = blockIdx.x / 144;
  int idx = bb*256 + threadIdx.x;
  if (idx >= NV*NV) return;
  int i = idx / NV, j = idx - i*NV;
  const int mat = part >> 4;
  const float* __restrict__ A = (mat==0)?Av:((mat==1)?Aa:Ap);
  const int r0 = (part & 15) * 75;
  float a0=0.f, a1=0.f, a2=0.f;
  #pragma unroll 5
  for (int r=r0; r<r0+75; r+=3) {
    a0 = fmaf(A[(size_t)r*NV+i],     A[(size_t)r*NV+j],     a0);
    a1 = fmaf(A[(size_t)(r+1)*NV+i], A[(size_t)(r+1)*NV+j], a1);
    a2 = fmaf(A[(size_t)(r+2)*NV+i], A[(size_t)(r+2)*NV+j], a2);
  }
  MP[(size_t)part*NV*NV + idx] = (a0 + a1) + a2;
}

// sum Gram partials (fixed order) and swizzle into MFMA A-frags (bf16 hi/lo)
__global__ __launch_bounds__(256) void kS(const float* __restrict__ MP,
    unsigned short* __restrict__ Mh, unsigned short* __restrict__ Ml) {
  int idx = blockIdx.x*256 + threadIdx.x;
  if (idx >= 12*6*512) return;
  int jj = idx&7, lane=(idx>>3)&63, kb=(idx>>9)%6, mb=(idx>>9)/6;
  int i = mb*16 + (lane&15), k = kb*32 + (lane>>4)*8 + jj;
  const size_t e = (size_t)i*NV + k;
  float v = 0.f;
  #pragma unroll
  for (int p=0;p<NPART;++p) v += MP[(size_t)p*NV*NV + e];
  unsigned short h,l; bsplit2(v, h, l);
  Mh[idx]=h; Ml[idx]=l;
}

// init: S0 = lamv+lama+lamp+cin [192][2048]; C0 = c0^T [192][2048];
// xh/xl = split(c0) [s][192]; QTinv frags
__global__ __launch_bounds__(256) void ki(const float* __restrict__ lam,
    const float* __restrict__ cin, const float* __restrict__ c0,
    const float* __restrict__ Qinv, float* __restrict__ S0, float* __restrict__ C0,
    unsigned short* __restrict__ xh, unsigned short* __restrict__ xl,
    unsigned short* __restrict__ QTh, unsigned short* __restrict__ QTl) {
  int idx = blockIdx.x*256 + threadIdx.x;
  if (idx < NV*B2) {
    int j = idx / B2, s = idx - j*B2;
    S0[idx] = lam[(size_t)s*576 + j] + lam[(size_t)s*576 + 192 + j]
            + lam[(size_t)s*576 + 384 + j] + cin[(size_t)s*NV + j];
    return;
  }
  idx -= NV*B2;
  if (idx < NV*B2) { int i = idx / B2, s = idx - i*B2; C0[idx] = c0[(size_t)s*NV + i]; return; }
  idx -= NV*B2;
  if (idx < NV*B2) {
    unsigned short h,l; bsplit2(c0[idx], h, l);   // same [s][192] linear layout
    xh[idx]=h; xl[idx]=l;
    return;
  }
  idx -= NV*B2;
  if (idx < 12*7*512) {
    int jj = idx&7, lane=(idx>>3)&63, kb=(idx>>9)%7, mb=(idx>>9)/7;
    int i = mb*16 + (lane&15), j = kb*32 + (lane>>4)*8 + jj;
    float v = (j < NTT) ? Qinv[(size_t)i*NTT + j] : 0.f;
    unsigned short h,l; bsplit2(v,h,l);
    QTh[idx]=h; QTl[idx]=l;
  }
}

// A operand swizzle (validated r2/r4/r6/r7/r8)
__global__ __launch_bounds__(256) void kA(const float* __restrict__ Av,
    const float* __restrict__ Aa, const float* __restrict__ Ap,
    unsigned short* __restrict__ Ah, unsigned short* __restrict__ Al,
    unsigned short* __restrict__ Ath, unsigned short* __restrict__ Atl) {
  int idx = blockIdx.x*256 + threadIdx.x;
  const int HALF = 3*80*6*512;
  if (idx >= 2*HALF) return;
  if (idx < HALF) {
    int j = idx&7, lane=(idx>>3)&63, kb=(idx>>9)%6, rb=(idx>>9)/6%80, mat=idx/(80*6*512);
    int row = rb*16 + (lane&15), col = kb*32 + (lane>>4)*8 + j;
    const float* A = (mat==0)?Av:((mat==1)?Aa:Ap);
    float v = (row < 1200) ? A[(size_t)row*NV + col] : 0.f;
    unsigned short h,l; bsplit2(v,h,l); Ah[idx]=h; Al[idx]=l;
  } else {
    int oi = idx - HALF;
    int jj = oi&7, lane=(oi>>3)&63, kbr=(oi>>9)%40, cb=(oi>>9)/40%12, mat=oi/(12*40*512);
    int row = kbr*32 + (lane>>4)*8 + jj, col = cb*16 + (lane&15);
    const float* A = (mat==0)?Av:((mat==1)?Aa:Ap);
    float v = (row < 1200) ? A[(size_t)row*NV + col] : 0.f;
    unsigned short h,l; bsplit2(v,h,l); Ath[oi]=h; Atl[oi]=l;
  }
}

// ---- kP: per-tile solve. grid = 128, block = 512. (unchanged from r7/r8) ----
__global__ __launch_bounds__(512) void kP(
    const float* __restrict__ Sin, float* __restrict__ Sout,
    const float* __restrict__ Cin, float* __restrict__ Cout,
    const float* __restrict__ beq,
    const float* __restrict__ dl, const float* __restrict__ sqP,
    unsigned short* __restrict__ xh, unsigned short* __restrict__ xl,
    const unsigned short* __restrict__ QTh, const unsigned short* __restrict__ QTl,
    const unsigned short* __restrict__ Mh, const unsigned short* __restrict__ Ml,
    float* __restrict__ tot, int upd)
{
  __shared__ unsigned short rhsH[16*KPAD], rhsL[16*KPAD];
  __shared__ float mxL[16*PMX];
  __shared__ float lamAcc[64];   // [0..47] dl-norm partials, [48..63] xdiff
  const int tid = threadIdx.x, wave = tid>>6, lane = tid&63;
  const int n = lane&15, q = lane>>4;
  const int tile0 = blockIdx.x*16, ts = tile0+n;

  if (tid<64) lamAcc[tid] = 0.f;

  s16x8 xfh[6], xfl[6];
  {
    const size_t xo = (size_t)ts*NV + q*8;
    #pragma unroll
    for (int kb=0;kb<6;++kb) {
      xfh[kb] = *(const s16x8*)(xh + xo + kb*32);
      xfl[kb] = *(const s16x8*)(xl + xo + kb*32);
    }
  }
  __syncthreads();
  // Mall * x
  #pragma unroll 1
  for (int mi=0;mi<2;++mi) {
    const int mb = wave + mi*8;
    if (mb>=12) break;
    f32x4 a0={0,0,0,0}, a1={0,0,0,0}, a2={0,0,0,0};
    #pragma unroll
    for (int kb=0;kb<6;++kb) {
      s16x8 mh = *(const s16x8*)(Mh + ((size_t)(mb*6+kb))*512 + lane*8);
      s16x8 ml = *(const s16x8*)(Ml + ((size_t)(mb*6+kb))*512 + lane*8);
      a0 = MFMA(mh, xfh[kb], a0);
      a1 = MFMA(mh, xfl[kb], a1);
      a2 = MFMA(ml, xfh[kb], a2);
    }
    #pragma unroll
    for (int r=0;r<4;++r) mxL[n*PMX + mb*16 + q*4 + r] = a0[r]+a1[r]+a2[r];
  }
  __syncthreads();
  // dl sums, S update, rhs build, lambda-norm partials
  {
    const int s = tid & 15, jg = tid >> 4;
    const int sg = tile0 + s;
    float l0=0.f, l1=0.f, l2=0.f;
    #pragma unroll 1
    for (int jp=0;jp<6;++jp) {
      const int j = jg + jp*32;
      float dm0=0.f, dm1=0.f, dm2=0.f;
      #pragma unroll
      for (int c=0;c<4;++c) {
        dm0 += dl[((size_t)c*576 + j)*B2 + sg];
        dm1 += dl[((size_t)c*576 + NV + j)*B2 + sg];
        dm2 += dl[((size_t)c*576 + 2*NV + j)*B2 + sg];
      }
      const float dsum = dm0+dm1+dm2;
      const float Sc = Sin[(size_t)j*B2 + sg];
      const float Sn = upd ? (Sc - dsum) : Sc;   // d=1: dl_0 is G-only, no lam update
      Sout[(size_t)j*B2 + sg] = Sn;
      const float rv = Sn + mxL[s*PMX + j] - dsum;   // = S_new + G
      unsigned short h,l; bsplit2(rv,h,l);
      rhsH[s*KPAD + j] = h; rhsL[s*KPAD + j] = l;
      l0 += dm0*dm0; l1 += dm1*dm1; l2 += dm2*dm2;
    }
    l0 += __shfl_xor(l0,16); l0 += __shfl_xor(l0,32);
    l1 += __shfl_xor(l1,16); l1 += __shfl_xor(l1,32);
    l2 += __shfl_xor(l2,16); l2 += __shfl_xor(l2,32);
    if (q==0 && upd) {
      atomicAdd(&lamAcc[n], l0);
      atomicAdd(&lamAcc[16+n], l1);
      atomicAdd(&lamAcc[32+n], l2);
    }
  }
  if (tid < 480) {
    const int je = tid>>4, sB = tid&15;
    unsigned short h,l; bsplit2(beq[(size_t)(tile0+sB)*30 + je], h, l);
    rhsH[sB*KPAD + NV + je] = h; rhsL[sB*KPAD + NV + je] = l;
  }
  if (tid < 160) {   // zero pad j = 222..231
    const int sB = tid&15, jt = NTT + (tid>>4);
    rhsH[sB*KPAD + jt] = 0; rhsL[sB*KPAD + jt] = 0;
  }
  __syncthreads();
  // Qinv MFMA -> primal
  s16x8 rfh[7], rfl[7];
  #pragma unroll
  for (int kb=0;kb<7;++kb) {
    rfh[kb] = *(const s16x8*)(rhsH + n*KPAD + kb*32 + q*8);
    rfl[kb] = *(const s16x8*)(rhsL + n*KPAD + kb*32 + q*8);
  }
  float xdl = 0.f;
  #pragma unroll 1
  for (int mi=0;mi<2;++mi) {
    const int mb = wave + mi*8;
    if (mb>=12) break;
    f32x4 a0={0,0,0,0}, a1={0,0,0,0}, a2={0,0,0,0};
    #pragma unroll
    for (int kb=0;kb<7;++kb) {
      s16x8 qh = *(const s16x8*)(QTh + ((size_t)(mb*7+kb))*512 + lane*8);
      s16x8 ql = *(const s16x8*)(QTl + ((size_t)(mb*7+kb))*512 + lane*8);
      a0 = MFMA(qh, rfh[kb], a0);
      a1 = MFMA(qh, rfl[kb], a1);
      a2 = MFMA(ql, rfh[kb], a2);
    }
    unsigned short xh4[4], xl4[4];
    #pragma unroll
    for (int r=0;r<4;++r) {
      const float xv = a0[r]+a1[r]+a2[r];
      const int i = mb*16 + q*4 + r;
      const float df = xv - Cin[(size_t)i*B2 + ts];
      xdl += df*df;
      Cout[(size_t)i*B2 + ts] = xv;
      bsplit2(xv, xh4[r], xl4[r]);
    }
    uint2 pk;
    pk.x = (unsigned)xh4[0] | ((unsigned)xh4[1]<<16);
    pk.y = (unsigned)xh4[2] | ((unsigned)xh4[3]<<16);
    *(uint2*)(xh + (size_t)ts*NV + mb*16 + q*4) = pk;
    pk.x = (unsigned)xl4[0] | ((unsigned)xl4[1]<<16);
    pk.y = (unsigned)xl4[2] | ((unsigned)xl4[3]<<16);
    *(uint2*)(xl + (size_t)ts*NV + mb*16 + q*4) = pk;
  }
  xdl += __shfl_xor(xdl,16); xdl += __shfl_xor(xdl,32);
  if (q==0) atomicAdd(&lamAcc[48+n], xdl);
  __syncthreads();
  // finalize tot: ||dl_{t-1}|| (upd) + res/sd_{t-1} (sqP; skipped at d=1) + xdiff_t
  if (tid < 16) {
    const int sg2 = tile0 + tid;
    float fp = sqrtf(lamAcc[tid]) + sqrtf(lamAcc[16+tid])
             + sqrtf(lamAcc[32+tid]) + sqrtf(lamAcc[48+tid]);
    float rp = 0.f;
    if (upd) {
      #pragma unroll
      for (int sl=0;sl<6;++sl) {
        float v = sqP[(size_t)sg2*8+sl] + sqP[16384+(size_t)sg2*8+sl]
                + sqP[2*16384+(size_t)sg2*8+sl] + sqP[3*16384+(size_t)sg2*8+sl];
        float nn = sqrtf(v);
        if (sl<3) rp += nn; else fp += nn;
      }
      tot[(size_t)sg2*2+0] += fp;
      tot[(size_t)sg2*2+1] += rp;
    } else {
      tot[(size_t)sg2*2+0] = fp;   // first iteration: initialize (ws is poisoned)
      tot[(size_t)sg2*2+1] = 0.f;
    }
  }
}

// ---- k2: A-streamer, MTILE=32, block=1024 (16 waves). grid = 256. ----
template<int FIRST>
__global__ __launch_bounds__(1024) void k2(
    const unsigned short* __restrict__ Ah, const unsigned short* __restrict__ Al,
    const unsigned short* __restrict__ Ath, const unsigned short* __restrict__ Atl,
    const unsigned short* __restrict__ xh, const unsigned short* __restrict__ xl,
    __half* __restrict__ uW, float* __restrict__ dl, float* __restrict__ sqP)
{
  __shared__ unsigned short rsh[32*PR], rsl[32*PR];
  __shared__ float sqAcc[192];   // [slot 6][sample 32]
  const int tid = threadIdx.x, wave = tid>>6, lane = tid&63;
  const int n = lane&15, q = lane>>4;
  const int tile = blockIdx.x >> 2, chunk = blockIdx.x & 3;
  const int tile0 = tile*32;

  if (tid < 192) sqAcc[tid] = 0.f;

  // x B-frags for both 16-sample groups
  s16x8 xfh[2][6], xfl[2][6];
  #pragma unroll
  for (int g=0;g<2;++g) {
    const size_t xo = (size_t)(tile0 + g*16 + n)*NV + q*8;
    #pragma unroll
    for (int kb=0;kb<6;++kb) {
      xfh[g][kb] = *(const s16x8*)(xh + xo + kb*32);
      xfl[g][kb] = *(const s16x8*)(xl + xo + kb*32);
    }
  }
  __syncthreads();

  #pragma unroll 1
  for (int mat=0; mat<3; ++mat) {
    const float b = (mat==0)?0.8f:((mat==1)?1.8f:3.14159265358979f);
    if (mat>0) __syncthreads();
    float rsq[2]={0.f,0.f}, ssq[2]={0.f,0.f};
    // fwd: v = A x, rs/u — A-frags loaded once, used for both groups
    #pragma unroll 1
    for (int ri=0; ri<2; ++ri) {
      const int rbl = wave + ri*16;
      if (rbl >= 20) break;
      const int rb = chunk*20 + rbl;
      f32x4 acc[2][3];
      #pragma unroll
      for (int g=0;g<2;++g)
        #pragma unroll
        for (int p=0;p<3;++p) acc[g][p] = (f32x4){0.f,0.f,0.f,0.f};
      const size_t ab = ((size_t)(mat*80+rb)*6)*512 + (size_t)lane*8;
      #pragma unroll
      for (int kb=0;kb<6;++kb) {
        s16x8 ah = *(const s16x8*)(Ah + ab + (size_t)kb*512);
        s16x8 al = *(const s16x8*)(Al + ab + (size_t)kb*512);
        #pragma unroll
        for (int g=0;g<2;++g) {
          acc[g][0] = MFMA(ah, xfh[g][kb], acc[g][0]);
          acc[g][1] = MFMA(ah, xfl[g][kb], acc[g][1]);
          acc[g][2] = MFMA(al, xfh[g][kb], acc[g][2]);
        }
      }
      #pragma unroll
      for (int g=0;g<2;++g) {
        unsigned short rh4[4], rl4[4];
        #pragma unroll
        for (int r4i=0;r4i<4;++r4i) {
          const float v = acc[g][0][r4i]+acc[g][1][r4i]+acc[g][2][r4i];
          const float rs = fmaxf(v-b, 0.f);
          const int r = rb*16 + q*4 + r4i;
          if (r < 1200) {
            const float u = fminf(v, b);
            const size_t ui = ((size_t)mat*1200 + r)*B2 + tile0 + g*16 + n;
            if (!FIRST) {
              const float sd = u - __half2float(uW[ui]);
              ssq[g] += sd*sd; rsq[g] += rs*rs;
            }
            uW[ui] = __float2half(u);
          }
          bsplit2(rs, rh4[r4i], rl4[r4i]);
        }
        const int lo = (g*16+n)*PR + rbl*16 + q*4;
        uint2 pk;
        pk.x = (unsigned)rh4[0] | ((unsigned)rh4[1]<<16);
        pk.y = (unsigned)rh4[2] | ((unsigned)rh4[3]<<16);
        *(uint2*)(rsh + lo) = pk;
        pk.x = (unsigned)rl4[0] | ((unsigned)rl4[1]<<16);
        pk.y = (unsigned)rl4[2] | ((unsigned)rl4[3]<<16);
        *(uint2*)(rsl + lo) = pk;
      }
    }
    if (!FIRST) {
      #pragma unroll
      for (int g=0;g<2;++g) {
        float r1 = rsq[g], s1 = ssq[g];
        r1 += __shfl_xor(r1,16); r1 += __shfl_xor(r1,32);
        s1 += __shfl_xor(s1,16); s1 += __shfl_xor(s1,32);
        if (q==0) {
          atomicAdd(&sqAcc[mat*32 + g*16 + n], r1);
          atomicAdd(&sqAcc[(3+mat)*32 + g*16 + n], s1);
        }
      }
    }
    __syncthreads();
    // transpose: dl = A^T rs (A-frags reused across both groups); cb = wave
    if (wave < 12) {
      const int cb = wave;
      f32x4 dacc[2][3];
      #pragma unroll
      for (int g=0;g<2;++g)
        #pragma unroll
        for (int p=0;p<3;++p) dacc[g][p] = (f32x4){0.f,0.f,0.f,0.f};
      const size_t tb = ((size_t)((mat*12+cb)*40) + chunk*10)*512 + (size_t)lane*8;
      #pragma unroll 2
      for (int kk=0;kk<10;++kk) {
        s16x8 th = *(const s16x8*)(Ath + tb + (size_t)kk*512);
        s16x8 tl = *(const s16x8*)(Atl + tb + (size_t)kk*512);
        #pragma unroll
        for (int g=0;g<2;++g) {
          const int lb = (g*16+n)*PR + q*8 + kk*32;
          s16x8 rh = *(const s16x8*)(rsh + lb);
          s16x8 rl = *(const s16x8*)(rsl + lb);
          dacc[g][0] = MFMA(th, rh, dacc[g][0]);
          dacc[g][1] = MFMA(th, rl, dacc[g][1]);
          dacc[g][2] = MFMA(tl, rh, dacc[g][2]);
        }
      }
      #pragma unroll
      for (int g=0;g<2;++g)
        #pragma unroll
        for (int r4i=0;r4i<4;++r4i)
          dl[((size_t)chunk*576 + mat*NV + cb*16 + q*4 + r4i)*B2 + tile0 + g*16 + n]
            = dacc[g][0][r4i]+dacc[g][1][r4i]+dacc[g][2][r4i];
    }
  }
  __syncthreads();
  if (!FIRST && tid<192) {
    int s = tid & 31, sl = tid >> 5;
    sqP[(size_t)chunk*16384 + (size_t)(tile0+s)*8 + sl] = sqAcc[sl*32+s];
  }
}

// finalize iteration-15 norms + outputs
__global__ __launch_bounds__(256) void k3(const float* __restrict__ dl,
    const float* __restrict__ sqP, const float* __restrict__ Cfin,
    const float* __restrict__ tot, float* __restrict__ out)
{
  __shared__ float sqL[8][4];
  const int tid = threadIdx.x;
  const int sb = blockIdx.x*8;
  if (tid<32) ((float*)sqL)[tid]=0.f;
  __syncthreads();
  for (int idx=tid; idx<8*576; idx+=256) {
    int s = idx&7, e = idx>>3;
    float v = 0.f;
    #pragma unroll
    for (int c=0;c<4;++c) v += dl[((size_t)c*576 + e)*B2 + sb + s];
    atomicAdd(&sqL[s][e/NV], v*v);
  }
  for (int idx=tid; idx<8*NV; idx+=256) {
    int s = idx/NV, i = idx - s*NV;
    out[(size_t)(sb+s)*NV + i] = Cfin[(size_t)i*B2 + sb + s];
  }
  __syncthreads();
  if (tid<8) {
    int s = tid, sg = sb+s;
    float fp = sqrtf(sqL[s][0]) + sqrtf(sqL[s][1]) + sqrtf(sqL[s][2]);
    float rp = 0.f;
    #pragma unroll
    for (int sl=0;sl<6;++sl) {
      float v = sqP[(size_t)sg*8+sl] + sqP[16384+(size_t)sg*8+sl]
              + sqP[2*16384+(size_t)sg*8+sl] + sqP[3*16384+(size_t)sg*8+sl];
      float nn = sqrtf(v);
      if (sl<3) rp += nn; else fp += nn;
    }
    fp += tot[(size_t)sg*2+0];
    rp += tot[(size_t)sg*2+1];
    out[(size_t)B2*NV + sg] = fp * (1.f/15.f);
    out[(size_t)B2*NV + B2 + sg] = rp * (1.f/15.f);
  }
}

extern "C" void kernel_launch(void* const* d_in, const int* in_sizes, int n_in,
                              void* d_out, int out_size, void* d_ws, size_t ws_size,
                              hipStream_t stream) {
  const float* lamda = (const float*)d_in[0];
  const float* cin   = (const float*)d_in[1];
  const float* c0    = (const float*)d_in[2];
  const float* beq   = (const float*)d_in[3];
  const float* Av    = (const float*)d_in[4];
  const float* Aa    = (const float*)d_in[5];
  const float* Ap    = (const float*)d_in[6];
  const float* Qinv  = (const float*)d_in[7];
  if (ws_size < (size_t)WS_FLOATS * sizeof(float)) return;

  float* ws = (float*)d_ws;
  float* S[2]  = { ws + O_S0, ws + O_S1 };
  float* C[2]  = { ws + O_C0, ws + O_C1 };
  __half* uW   = (__half*)(ws + O_U);
  float* dl    = ws + O_DL;
  float* sqP   = ws + O_SQP;
  float* tot   = ws + O_TOT;
  unsigned short* xh  = (unsigned short*)(ws + O_XH);
  unsigned short* xl  = (unsigned short*)(ws + O_XL);
  unsigned short* Ah  = (unsigned short*)(ws + O_AH);
  unsigned short* Al  = (unsigned short*)(ws + O_AL);
  unsigned short* Ath = (unsigned short*)(ws + O_ATH);
  unsigned short* Atl = (unsigned short*)(ws + O_ATL);
  unsigned short* QTh = (unsigned short*)(ws + O_QTH);
  unsigned short* QTl = (unsigned short*)(ws + O_QTL);
  unsigned short* Mh  = (unsigned short*)(ws + O_MH);
  unsigned short* Ml  = (unsigned short*)(ws + O_ML2);
  float* MP = ws + O_MP;
  float* out = (float*)d_out;

  kM<<<NPART*144, 256, 0, stream>>>(Av, Aa, Ap, MP);
  kS<<<144, 256, 0, stream>>>(MP, Mh, Ml);
  ki<<<(3*NV*B2 + 12*7*512 + 255)/256, 256, 0, stream>>>(lamda, cin, c0, Qinv,
      S[0], C[0], xh, xl, QTh, QTl);
  kA<<<(2*3*80*6*512 + 255)/256, 256, 0, stream>>>(Av, Aa, Ap, Ah, Al, Ath, Atl);

  // prime: u_0 and dl_0 = A^T relu(A c0 - b) from x = c0
  k2<1><<<256, 1024, 0, stream>>>(Ah, Al, Ath, Atl, xh, xl, uW, dl, sqP);
  for (int d = 1; d <= 15; ++d) {
    kP<<<128, 512, 0, stream>>>(S[(d+1)&1], S[d&1], C[(d+1)&1], C[d&1], beq,
        dl, sqP, xh, xl, QTh, QTl, Mh, Ml, tot, (d>=2)?1:0);
    k2<0><<<256, 1024, 0, stream>>>(Ah, Al, Ath, Atl, xh, xl, uW, dl, sqP);
  }
  k3<<<256, 256, 0, stream>>>(dl, sqP, C[1], tot, out);
}

// Round 10
// 1462.239 us; speedup vs baseline: 1.0730x; 1.0730x over previous
//
#include <hip/hip_runtime.h>
#include <hip/hip_fp16.h>

// MLPProjectionFilter round 10 = round-8 (validated) with k2 mat-split:
// grid = 3*64*4 = 768 WGs of 512 threads, each WG handles ONE matrix's
// fwd + transpose for its (tile,chunk). r9's block=1024 forced VGPR 64 ->
// scratch spills (FETCH 23->91 MB, 78 us). r8 was structurally capped at
// 1 WG/CU because grid == 256; mat-split gives 2 WGs/CU (16 waves) with the
// same 104-VGPR 42-KB-LDS kernel and unchanged A traffic.
// Per iter: kP (per-tile: dl-sum, S/lambda, G=Mall*x-dlsum, rhs, Qinv MFMA,
// norms) then k2 (A-stream: v=Ax fwd + dl=A^T rs transpose, split-bf16 MFMA).

typedef short s16x8 __attribute__((ext_vector_type(8)));
typedef float f32x4 __attribute__((ext_vector_type(4)));
#define MFMA(a,b,c) __builtin_amdgcn_mfma_f32_16x16x32_bf16(a,b,c,0,0,0)

#define B2 2048
#define NV 192
#define NTT 222
#define KPAD 232
#define PR 328        // k2 rs LDS pitch (ushort), 320 rows/chunk + pad
#define PMX 200       // kP mxL pitch (f32)
#define NPART 48      // Gram partials

// ---- ws layout (float offsets) ----
#define O_S0  0u
#define O_S1  393216u
#define O_C0  786432u
#define O_C1  1179648u
#define O_U   1572864u     // __half[3*1200*2048] = 3,686,400 fl
#define O_DL  5259264u     // f32 [4][576][2048] = 4,718,592
#define O_SQP 9977856u     // f32 [4][2048][8] = 65,536
#define O_TOT 10043392u    // f32 [2048][2] = 4,096
#define O_XH  10047488u    // ushort[2048*192] = 196,608 fl
#define O_XL  10244096u
#define O_AH  10440704u    // ushort[3*80*6*512] = 368,640 fl each
#define O_AL  10809344u
#define O_ATH 11177984u
#define O_ATL 11546624u
#define O_QTH 11915264u    // ushort[12*7*512] = 21,504 fl
#define O_QTL 11936768u
#define O_MH  11958272u    // ushort[12*6*512] = 18,432 fl
#define O_ML2 11976704u
#define O_MP  11995136u    // f32 [48][192*192] Gram partials = 1,769,472
#define WS_FLOATS 13764608u  // 55.1 MB

__device__ inline unsigned short bh16(float v){
  union{float f; unsigned u;} a; a.f=v;
  return (unsigned short)((a.u + 0x7FFFu + ((a.u>>16)&1u))>>16);
}
__device__ inline void bsplit2(float v, unsigned short& h, unsigned short& l){
  h = bh16(v);
  union{unsigned u; float f;} hf; hf.u = ((unsigned)h)<<16;
  l = bh16(v - hf.f);
}

// Gram partials: MP[part][i*NV+j], part = mat*16 + rblk, rows [rblk*75, +75).
// Deterministic (no atomics), 3 independent FMA chains.
__global__ __launch_bounds__(256) void kM(const float* __restrict__ Av,
    const float* __restrict__ Aa, const float* __restrict__ Ap, float* __restrict__ MP) {
  int bb = blockIdx.x % 144, part = blockIdx.x / 144;
  int idx = bb*256 + threadIdx.x;
  if (idx >= NV*NV) return;
  int i = idx / NV, j = idx - i*NV;
  const int mat = part >> 4;
  const float* __restrict__ A = (mat==0)?Av:((mat==1)?Aa:Ap);
  const int r0 = (part & 15) * 75;
  float a0=0.f, a1=0.f, a2=0.f;
  #pragma unroll 5
  for (int r=r0; r<r0+75; r+=3) {
    a0 = fmaf(A[(size_t)r*NV+i],     A[(size_t)r*NV+j],     a0);
    a1 = fmaf(A[(size_t)(r+1)*NV+i], A[(size_t)(r+1)*NV+j], a1);
    a2 = fmaf(A[(size_t)(r+2)*NV+i], A[(size_t)(r+2)*NV+j], a2);
  }
  MP[(size_t)part*NV*NV + idx] = (a0 + a1) + a2;
}

// sum Gram partials (fixed order) and swizzle into MFMA A-frags (bf16 hi/lo)
__global__ __launch_bounds__(256) void kS(const float* __restrict__ MP,
    unsigned short* __restrict__ Mh, unsigned short* __restrict__ Ml) {
  int idx = blockIdx.x*256 + threadIdx.x;
  if (idx >= 12*6*512) return;
  int jj = idx&7, lane=(idx>>3)&63, kb=(idx>>9)%6, mb=(idx>>9)/6;
  int i = mb*16 + (lane&15), k = kb*32 + (lane>>4)*8 + jj;
  const size_t e = (size_t)i*NV + k;
  float v = 0.f;
  #pragma unroll
  for (int p=0;p<NPART;++p) v += MP[(size_t)p*NV*NV + e];
  unsigned short h,l; bsplit2(v, h, l);
  Mh[idx]=h; Ml[idx]=l;
}

// init: S0 = lamv+lama+lamp+cin [192][2048]; C0 = c0^T [192][2048];
// xh/xl = split(c0) [s][192]; QTinv frags
__global__ __launch_bounds__(256) void ki(const float* __restrict__ lam,
    const float* __restrict__ cin, const float* __restrict__ c0,
    const float* __restrict__ Qinv, float* __restrict__ S0, float* __restrict__ C0,
    unsigned short* __restrict__ xh, unsigned short* __restrict__ xl,
    unsigned short* __restrict__ QTh, unsigned short* __restrict__ QTl) {
  int idx = blockIdx.x*256 + threadIdx.x;
  if (idx < NV*B2) {
    int j = idx / B2, s = idx - j*B2;
    S0[idx] = lam[(size_t)s*576 + j] + lam[(size_t)s*576 + 192 + j]
            + lam[(size_t)s*576 + 384 + j] + cin[(size_t)s*NV + j];
    return;
  }
  idx -= NV*B2;
  if (idx < NV*B2) { int i = idx / B2, s = idx - i*B2; C0[idx] = c0[(size_t)s*NV + i]; return; }
  idx -= NV*B2;
  if (idx < NV*B2) {
    unsigned short h,l; bsplit2(c0[idx], h, l);   // same [s][192] linear layout
    xh[idx]=h; xl[idx]=l;
    return;
  }
  idx -= NV*B2;
  if (idx < 12*7*512) {
    int jj = idx&7, lane=(idx>>3)&63, kb=(idx>>9)%7, mb=(idx>>9)/7;
    int i = mb*16 + (lane&15), j = kb*32 + (lane>>4)*8 + jj;
    float v = (j < NTT) ? Qinv[(size_t)i*NTT + j] : 0.f;
    unsigned short h,l; bsplit2(v,h,l);
    QTh[idx]=h; QTl[idx]=l;
  }
}

// A operand swizzle (validated r2/r4/r6/r7/r8)
__global__ __launch_bounds__(256) void kA(const float* __restrict__ Av,
    const float* __restrict__ Aa, const float* __restrict__ Ap,
    unsigned short* __restrict__ Ah, unsigned short* __restrict__ Al,
    unsigned short* __restrict__ Ath, unsigned short* __restrict__ Atl) {
  int idx = blockIdx.x*256 + threadIdx.x;
  const int HALF = 3*80*6*512;
  if (idx >= 2*HALF) return;
  if (idx < HALF) {
    int j = idx&7, lane=(idx>>3)&63, kb=(idx>>9)%6, rb=(idx>>9)/6%80, mat=idx/(80*6*512);
    int row = rb*16 + (lane&15), col = kb*32 + (lane>>4)*8 + j;
    const float* A = (mat==0)?Av:((mat==1)?Aa:Ap);
    float v = (row < 1200) ? A[(size_t)row*NV + col] : 0.f;
    unsigned short h,l; bsplit2(v,h,l); Ah[idx]=h; Al[idx]=l;
  } else {
    int oi = idx - HALF;
    int jj = oi&7, lane=(oi>>3)&63, kbr=(oi>>9)%40, cb=(oi>>9)/40%12, mat=oi/(12*40*512);
    int row = kbr*32 + (lane>>4)*8 + jj, col = cb*16 + (lane&15);
    const float* A = (mat==0)?Av:((mat==1)?Aa:Ap);
    float v = (row < 1200) ? A[(size_t)row*NV + col] : 0.f;
    unsigned short h,l; bsplit2(v,h,l); Ath[oi]=h; Atl[oi]=l;
  }
}

// ---- kP: per-tile solve. grid = 128, block = 512. (unchanged from r7/r8) ----
__global__ __launch_bounds__(512) void kP(
    const float* __restrict__ Sin, float* __restrict__ Sout,
    const float* __restrict__ Cin, float* __restrict__ Cout,
    const float* __restrict__ beq,
    const float* __restrict__ dl, const float* __restrict__ sqP,
    unsigned short* __restrict__ xh, unsigned short* __restrict__ xl,
    const unsigned short* __restrict__ QTh, const unsigned short* __restrict__ QTl,
    const unsigned short* __restrict__ Mh, const unsigned short* __restrict__ Ml,
    float* __restrict__ tot, int upd)
{
  __shared__ unsigned short rhsH[16*KPAD], rhsL[16*KPAD];
  __shared__ float mxL[16*PMX];
  __shared__ float lamAcc[64];   // [0..47] dl-norm partials, [48..63] xdiff
  const int tid = threadIdx.x, wave = tid>>6, lane = tid&63;
  const int n = lane&15, q = lane>>4;
  const int tile0 = blockIdx.x*16, ts = tile0+n;

  if (tid<64) lamAcc[tid] = 0.f;

  s16x8 xfh[6], xfl[6];
  {
    const size_t xo = (size_t)ts*NV + q*8;
    #pragma unroll
    for (int kb=0;kb<6;++kb) {
      xfh[kb] = *(const s16x8*)(xh + xo + kb*32);
      xfl[kb] = *(const s16x8*)(xl + xo + kb*32);
    }
  }
  __syncthreads();
  // Mall * x
  #pragma unroll 1
  for (int mi=0;mi<2;++mi) {
    const int mb = wave + mi*8;
    if (mb>=12) break;
    f32x4 a0={0,0,0,0}, a1={0,0,0,0}, a2={0,0,0,0};
    #pragma unroll
    for (int kb=0;kb<6;++kb) {
      s16x8 mh = *(const s16x8*)(Mh + ((size_t)(mb*6+kb))*512 + lane*8);
      s16x8 ml = *(const s16x8*)(Ml + ((size_t)(mb*6+kb))*512 + lane*8);
      a0 = MFMA(mh, xfh[kb], a0);
      a1 = MFMA(mh, xfl[kb], a1);
      a2 = MFMA(ml, xfh[kb], a2);
    }
    #pragma unroll
    for (int r=0;r<4;++r) mxL[n*PMX + mb*16 + q*4 + r] = a0[r]+a1[r]+a2[r];
  }
  __syncthreads();
  // dl sums, S update, rhs build, lambda-norm partials
  {
    const int s = tid & 15, jg = tid >> 4;
    const int sg = tile0 + s;
    float l0=0.f, l1=0.f, l2=0.f;
    #pragma unroll 1
    for (int jp=0;jp<6;++jp) {
      const int j = jg + jp*32;
      float dm0=0.f, dm1=0.f, dm2=0.f;
      #pragma unroll
      for (int c=0;c<4;++c) {
        dm0 += dl[((size_t)c*576 + j)*B2 + sg];
        dm1 += dl[((size_t)c*576 + NV + j)*B2 + sg];
        dm2 += dl[((size_t)c*576 + 2*NV + j)*B2 + sg];
      }
      const float dsum = dm0+dm1+dm2;
      const float Sc = Sin[(size_t)j*B2 + sg];
      const float Sn = upd ? (Sc - dsum) : Sc;   // d=1: dl_0 is G-only, no lam update
      Sout[(size_t)j*B2 + sg] = Sn;
      const float rv = Sn + mxL[s*PMX + j] - dsum;   // = S_new + G
      unsigned short h,l; bsplit2(rv,h,l);
      rhsH[s*KPAD + j] = h; rhsL[s*KPAD + j] = l;
      l0 += dm0*dm0; l1 += dm1*dm1; l2 += dm2*dm2;
    }
    l0 += __shfl_xor(l0,16); l0 += __shfl_xor(l0,32);
    l1 += __shfl_xor(l1,16); l1 += __shfl_xor(l1,32);
    l2 += __shfl_xor(l2,16); l2 += __shfl_xor(l2,32);
    if (q==0 && upd) {
      atomicAdd(&lamAcc[n], l0);
      atomicAdd(&lamAcc[16+n], l1);
      atomicAdd(&lamAcc[32+n], l2);
    }
  }
  if (tid < 480) {
    const int je = tid>>4, sB = tid&15;
    unsigned short h,l; bsplit2(beq[(size_t)(tile0+sB)*30 + je], h, l);
    rhsH[sB*KPAD + NV + je] = h; rhsL[sB*KPAD + NV + je] = l;
  }
  if (tid < 160) {   // zero pad j = 222..231
    const int sB = tid&15, jt = NTT + (tid>>4);
    rhsH[sB*KPAD + jt] = 0; rhsL[sB*KPAD + jt] = 0;
  }
  __syncthreads();
  // Qinv MFMA -> primal
  s16x8 rfh[7], rfl[7];
  #pragma unroll
  for (int kb=0;kb<7;++kb) {
    rfh[kb] = *(const s16x8*)(rhsH + n*KPAD + kb*32 + q*8);
    rfl[kb] = *(const s16x8*)(rhsL + n*KPAD + kb*32 + q*8);
  }
  float xdl = 0.f;
  #pragma unroll 1
  for (int mi=0;mi<2;++mi) {
    const int mb = wave + mi*8;
    if (mb>=12) break;
    f32x4 a0={0,0,0,0}, a1={0,0,0,0}, a2={0,0,0,0};
    #pragma unroll
    for (int kb=0;kb<7;++kb) {
      s16x8 qh = *(const s16x8*)(QTh + ((size_t)(mb*7+kb))*512 + lane*8);
      s16x8 ql = *(const s16x8*)(QTl + ((size_t)(mb*7+kb))*512 + lane*8);
      a0 = MFMA(qh, rfh[kb], a0);
      a1 = MFMA(qh, rfl[kb], a1);
      a2 = MFMA(ql, rfh[kb], a2);
    }
    unsigned short xh4[4], xl4[4];
    #pragma unroll
    for (int r=0;r<4;++r) {
      const float xv = a0[r]+a1[r]+a2[r];
      const int i = mb*16 + q*4 + r;
      const float df = xv - Cin[(size_t)i*B2 + ts];
      xdl += df*df;
      Cout[(size_t)i*B2 + ts] = xv;
      bsplit2(xv, xh4[r], xl4[r]);
    }
    uint2 pk;
    pk.x = (unsigned)xh4[0] | ((unsigned)xh4[1]<<16);
    pk.y = (unsigned)xh4[2] | ((unsigned)xh4[3]<<16);
    *(uint2*)(xh + (size_t)ts*NV + mb*16 + q*4) = pk;
    pk.x = (unsigned)xl4[0] | ((unsigned)xl4[1]<<16);
    pk.y = (unsigned)xl4[2] | ((unsigned)xl4[3]<<16);
    *(uint2*)(xl + (size_t)ts*NV + mb*16 + q*4) = pk;
  }
  xdl += __shfl_xor(xdl,16); xdl += __shfl_xor(xdl,32);
  if (q==0) atomicAdd(&lamAcc[48+n], xdl);
  __syncthreads();
  // finalize tot: ||dl_{t-1}|| (upd) + res/sd_{t-1} (sqP; skipped at d=1) + xdiff_t
  if (tid < 16) {
    const int sg2 = tile0 + tid;
    float fp = sqrtf(lamAcc[tid]) + sqrtf(lamAcc[16+tid])
             + sqrtf(lamAcc[32+tid]) + sqrtf(lamAcc[48+tid]);
    float rp = 0.f;
    if (upd) {
      #pragma unroll
      for (int sl=0;sl<6;++sl) {
        float v = sqP[(size_t)sg2*8+sl] + sqP[16384+(size_t)sg2*8+sl]
                + sqP[2*16384+(size_t)sg2*8+sl] + sqP[3*16384+(size_t)sg2*8+sl];
        float nn = sqrtf(v);
        if (sl<3) rp += nn; else fp += nn;
      }
      tot[(size_t)sg2*2+0] += fp;
      tot[(size_t)sg2*2+1] += rp;
    } else {
      tot[(size_t)sg2*2+0] = fp;   // first iteration: initialize (ws is poisoned)
      tot[(size_t)sg2*2+1] = 0.f;
    }
  }
}

// ---- k2: A-streamer, MTILE=32, mat-split. grid = 768 (mat*256 + tile*4 + chunk),
// block = 512. Each WG: one mat's fwd (20 row-blocks) + transpose (12 col-blocks).
template<int FIRST>
__global__ __launch_bounds__(512) void k2(
    const unsigned short* __restrict__ Ah, const unsigned short* __restrict__ Al,
    const unsigned short* __restrict__ Ath, const unsigned short* __restrict__ Atl,
    const unsigned short* __restrict__ xh, const unsigned short* __restrict__ xl,
    __half* __restrict__ uW, float* __restrict__ dl, float* __restrict__ sqP)
{
  __shared__ unsigned short rsh[32*PR], rsl[32*PR];
  __shared__ float sqAcc[64];   // [res/sd][sample 32] for this mat
  const int tid = threadIdx.x, wave = tid>>6, lane = tid&63;
  const int n = lane&15, q = lane>>4;
  const int mat = blockIdx.x >> 8;
  const int rest = blockIdx.x & 255;
  const int tile = rest >> 2, chunk = rest & 3;
  const int tile0 = tile*32;
  const float b = (mat==0)?0.8f:((mat==1)?1.8f:3.14159265358979f);

  if (tid < 64) sqAcc[tid] = 0.f;

  // x B-frags for both 16-sample groups
  s16x8 xfh[2][6], xfl[2][6];
  #pragma unroll
  for (int g=0;g<2;++g) {
    const size_t xo = (size_t)(tile0 + g*16 + n)*NV + q*8;
    #pragma unroll
    for (int kb=0;kb<6;++kb) {
      xfh[g][kb] = *(const s16x8*)(xh + xo + kb*32);
      xfl[g][kb] = *(const s16x8*)(xl + xo + kb*32);
    }
  }
  __syncthreads();

  float rsq[2]={0.f,0.f}, ssq[2]={0.f,0.f};
  // fwd: v = A x, rs/u — A-frags loaded once, used for both groups
  #pragma unroll 1
  for (int ri=0; ri<3; ++ri) {
    const int rbl = wave + ri*8;
    if (rbl >= 20) break;
    const int rb = chunk*20 + rbl;
    f32x4 acc[2][3];
    #pragma unroll
    for (int g=0;g<2;++g)
      #pragma unroll
      for (int p=0;p<3;++p) acc[g][p] = (f32x4){0.f,0.f,0.f,0.f};
    const size_t ab = ((size_t)(mat*80+rb)*6)*512 + (size_t)lane*8;
    #pragma unroll
    for (int kb=0;kb<6;++kb) {
      s16x8 ah = *(const s16x8*)(Ah + ab + (size_t)kb*512);
      s16x8 al = *(const s16x8*)(Al + ab + (size_t)kb*512);
      #pragma unroll
      for (int g=0;g<2;++g) {
        acc[g][0] = MFMA(ah, xfh[g][kb], acc[g][0]);
        acc[g][1] = MFMA(ah, xfl[g][kb], acc[g][1]);
        acc[g][2] = MFMA(al, xfh[g][kb], acc[g][2]);
      }
    }
    #pragma unroll
    for (int g=0;g<2;++g) {
      unsigned short rh4[4], rl4[4];
      #pragma unroll
      for (int r4i=0;r4i<4;++r4i) {
        const float v = acc[g][0][r4i]+acc[g][1][r4i]+acc[g][2][r4i];
        const float rs = fmaxf(v-b, 0.f);
        const int r = rb*16 + q*4 + r4i;
        if (r < 1200) {
          const float u = fminf(v, b);
          const size_t ui = ((size_t)mat*1200 + r)*B2 + tile0 + g*16 + n;
          if (!FIRST) {
            const float sd = u - __half2float(uW[ui]);
            ssq[g] += sd*sd; rsq[g] += rs*rs;
          }
          uW[ui] = __float2half(u);
        }
        bsplit2(rs, rh4[r4i], rl4[r4i]);
      }
      const int lo = (g*16+n)*PR + rbl*16 + q*4;
      uint2 pk;
      pk.x = (unsigned)rh4[0] | ((unsigned)rh4[1]<<16);
      pk.y = (unsigned)rh4[2] | ((unsigned)rh4[3]<<16);
      *(uint2*)(rsh + lo) = pk;
      pk.x = (unsigned)rl4[0] | ((unsigned)rl4[1]<<16);
      pk.y = (unsigned)rl4[2] | ((unsigned)rl4[3]<<16);
      *(uint2*)(rsl + lo) = pk;
    }
  }
  if (!FIRST) {
    #pragma unroll
    for (int g=0;g<2;++g) {
      float r1 = rsq[g], s1 = ssq[g];
      r1 += __shfl_xor(r1,16); r1 += __shfl_xor(r1,32);
      s1 += __shfl_xor(s1,16); s1 += __shfl_xor(s1,32);
      if (q==0) {
        atomicAdd(&sqAcc[g*16 + n], r1);
        atomicAdd(&sqAcc[32 + g*16 + n], s1);
      }
    }
  }
  __syncthreads();
  // transpose: dl = A^T rs (A-frags reused across both groups)
  #pragma unroll 1
  for (int ci=0; ci<2; ++ci) {
    const int cb = wave + ci*8;
    if (cb >= 12) break;
    f32x4 dacc[2][3];
    #pragma unroll
    for (int g=0;g<2;++g)
      #pragma unroll
      for (int p=0;p<3;++p) dacc[g][p] = (f32x4){0.f,0.f,0.f,0.f};
    const size_t tb = ((size_t)((mat*12+cb)*40) + chunk*10)*512 + (size_t)lane*8;
    #pragma unroll 2
    for (int kk=0;kk<10;++kk) {
      s16x8 th = *(const s16x8*)(Ath + tb + (size_t)kk*512);
      s16x8 tl = *(const s16x8*)(Atl + tb + (size_t)kk*512);
      #pragma unroll
      for (int g=0;g<2;++g) {
        const int lb = (g*16+n)*PR + q*8 + kk*32;
        s16x8 rh = *(const s16x8*)(rsh + lb);
        s16x8 rl = *(const s16x8*)(rsl + lb);
        dacc[g][0] = MFMA(th, rh, dacc[g][0]);
        dacc[g][1] = MFMA(th, rl, dacc[g][1]);
        dacc[g][2] = MFMA(tl, rh, dacc[g][2]);
      }
    }
    #pragma unroll
    for (int g=0;g<2;++g)
      #pragma unroll
      for (int r4i=0;r4i<4;++r4i)
        dl[((size_t)chunk*576 + mat*NV + cb*16 + q*4 + r4i)*B2 + tile0 + g*16 + n]
          = dacc[g][0][r4i]+dacc[g][1][r4i]+dacc[g][2][r4i];
  }
  __syncthreads();
  if (!FIRST && tid<64) {
    int s = tid & 31, half = tid >> 5;
    int sl = half ? (3 + mat) : mat;
    sqP[(size_t)chunk*16384 + (size_t)(tile0+s)*8 + sl] = sqAcc[half*32 + s];
  }
}

// finalize iteration-15 norms + outputs
__global__ __launch_bounds__(256) void k3(const float* __restrict__ dl,
    const float* __restrict__ sqP, const float* __restrict__ Cfin,
    const float* __restrict__ tot, float* __restrict__ out)
{
  __shared__ float sqL[8][4];
  const int tid = threadIdx.x;
  const int sb = blockIdx.x*8;
  if (tid<32) ((float*)sqL)[tid]=0.f;
  __syncthreads();
  for (int idx=tid; idx<8*576; idx+=256) {
    int s = idx&7, e = idx>>3;
    float v = 0.f;
    #pragma unroll
    for (int c=0;c<4;++c) v += dl[((size_t)c*576 + e)*B2 + sb + s];
    atomicAdd(&sqL[s][e/NV], v*v);
  }
  for (int idx=tid; idx<8*NV; idx+=256) {
    int s = idx/NV, i = idx - s*NV;
    out[(size_t)(sb+s)*NV + i] = Cfin[(size_t)i*B2 + sb + s];
  }
  __syncthreads();
  if (tid<8) {
    int s = tid, sg = sb+s;
    float fp = sqrtf(sqL[s][0]) + sqrtf(sqL[s][1]) + sqrtf(sqL[s][2]);
    float rp = 0.f;
    #pragma unroll
    for (int sl=0;sl<6;++sl) {
      float v = sqP[(size_t)sg*8+sl] + sqP[16384+(size_t)sg*8+sl]
              + sqP[2*16384+(size_t)sg*8+sl] + sqP[3*16384+(size_t)sg*8+sl];
      float nn = sqrtf(v);
      if (sl<3) rp += nn; else fp += nn;
    }
    fp += tot[(size_t)sg*2+0];
    rp += tot[(size_t)sg*2+1];
    out[(size_t)B2*NV + sg] = fp * (1.f/15.f);
    out[(size_t)B2*NV + B2 + sg] = rp * (1.f/15.f);
  }
}

extern "C" void kernel_launch(void* const* d_in, const int* in_sizes, int n_in,
                              void* d_out, int out_size, void* d_ws, size_t ws_size,
                              hipStream_t stream) {
  const float* lamda = (const float*)d_in[0];
  const float* cin   = (const float*)d_in[1];
  const float* c0    = (const float*)d_in[2];
  const float* beq   = (const float*)d_in[3];
  const float* Av    = (const float*)d_in[4];
  const float* Aa    = (const float*)d_in[5];
  const float* Ap    = (const float*)d_in[6];
  const float* Qinv  = (const float*)d_in[7];
  if (ws_size < (size_t)WS_FLOATS * sizeof(float)) return;

  float* ws = (float*)d_ws;
  float* S[2]  = { ws + O_S0, ws + O_S1 };
  float* C[2]  = { ws + O_C0, ws + O_C1 };
  __half* uW   = (__half*)(ws + O_U);
  float* dl    = ws + O_DL;
  float* sqP   = ws + O_SQP;
  float* tot   = ws + O_TOT;
  unsigned short* xh  = (unsigned short*)(ws + O_XH);
  unsigned short* xl  = (unsigned short*)(ws + O_XL);
  unsigned short* Ah  = (unsigned short*)(ws + O_AH);
  unsigned short* Al  = (unsigned short*)(ws + O_AL);
  unsigned short* Ath = (unsigned short*)(ws + O_ATH);
  unsigned short* Atl = (unsigned short*)(ws + O_ATL);
  unsigned short* QTh = (unsigned short*)(ws + O_QTH);
  unsigned short* QTl = (unsigned short*)(ws + O_QTL);
  unsigned short* Mh  = (unsigned short*)(ws + O_MH);
  unsigned short* Ml  = (unsigned short*)(ws + O_ML2);
  float* MP = ws + O_MP;
  float* out = (float*)d_out;

  kM<<<NPART*144, 256, 0, stream>>>(Av, Aa, Ap, MP);
  kS<<<144, 256, 0, stream>>>(MP, Mh, Ml);
  ki<<<(3*NV*B2 + 12*7*512 + 255)/256, 256, 0, stream>>>(lamda, cin, c0, Qinv,
      S[0], C[0], xh, xl, QTh, QTl);
  kA<<<(2*3*80*6*512 + 255)/256, 256, 0, stream>>>(Av, Aa, Ap, Ah, Al, Ath, Atl);

  // prime: u_0 and dl_0 = A^T relu(A c0 - b) from x = c0
  k2<1><<<768, 512, 0, stream>>>(Ah, Al, Ath, Atl, xh, xl, uW, dl, sqP);
  for (int d = 1; d <= 15; ++d) {
    kP<<<128, 512, 0, stream>>>(S[(d+1)&1], S[d&1], C[(d+1)&1], C[d&1], beq,
        dl, sqP, xh, xl, QTh, QTl, Mh, Ml, tot, (d>=2)?1:0);
    k2<0><<<768, 512, 0, stream>>>(Ah, Al, Ath, Atl, xh, xl, uW, dl, sqP);
  }
  k3<<<256, 256, 0, stream>>>(dl, sqP, C[1], tot, out);
}

// Round 11
// 1360.198 us; speedup vs baseline: 1.1535x; 1.0750x over previous
//
#include <hip/hip_runtime.h>
#include <hip/hip_fp16.h>

// MLPProjectionFilter round 11 = round-10 with k2 at MTILE=16 + mat-split +
// __launch_bounds__(512,4). Theory: reported VGPR excludes MFMA accumulators
// (unified file) -> true ~170 regs -> 2 waves/SIMD cap -> 1 WG/CU in r7-r10
// (Occupancy stuck ~20%). r9 forced 128 via block=1024 but spilled. MTILE=16
// genuinely needs ~95 regs (x-frags 48 not 96) so 4 waves/SIMD fits
// spill-free: grid 1536, 2 WGs/CU, 16 waves/CU.
// Per iter: kP (per-tile: dl-sum, S/lambda, G=Mall*x-dlsum, rhs, Qinv MFMA,
// norms) then k2 (A-stream: v=Ax fwd + dl=A^T rs transpose, split-bf16 MFMA).

typedef short s16x8 __attribute__((ext_vector_type(8)));
typedef float f32x4 __attribute__((ext_vector_type(4)));
#define MFMA(a,b,c) __builtin_amdgcn_mfma_f32_16x16x32_bf16(a,b,c,0,0,0)

#define B2 2048
#define NV 192
#define NTT 222
#define KPAD 232
#define PR 328        // k2 rs LDS pitch (ushort), 320 rows/chunk + pad
#define PMX 200       // kP mxL pitch (f32)
#define NPART 48      // Gram partials

// ---- ws layout (float offsets) ----
#define O_S0  0u
#define O_S1  393216u
#define O_C0  786432u
#define O_C1  1179648u
#define O_U   1572864u     // __half[3*1200*2048] = 3,686,400 fl
#define O_DL  5259264u     // f32 [4][576][2048] = 4,718,592
#define O_SQP 9977856u     // f32 [4][2048][8] = 65,536
#define O_TOT 10043392u    // f32 [2048][2] = 4,096
#define O_XH  10047488u    // ushort[2048*192] = 196,608 fl
#define O_XL  10244096u
#define O_AH  10440704u    // ushort[3*80*6*512] = 368,640 fl each
#define O_AL  10809344u
#define O_ATH 11177984u
#define O_ATL 11546624u
#define O_QTH 11915264u    // ushort[12*7*512] = 21,504 fl
#define O_QTL 11936768u
#define O_MH  11958272u    // ushort[12*6*512] = 18,432 fl
#define O_ML2 11976704u
#define O_MP  11995136u    // f32 [48][192*192] Gram partials = 1,769,472
#define WS_FLOATS 13764608u  // 55.1 MB

__device__ inline unsigned short bh16(float v){
  union{float f; unsigned u;} a; a.f=v;
  return (unsigned short)((a.u + 0x7FFFu + ((a.u>>16)&1u))>>16);
}
__device__ inline void bsplit2(float v, unsigned short& h, unsigned short& l){
  h = bh16(v);
  union{unsigned u; float f;} hf; hf.u = ((unsigned)h)<<16;
  l = bh16(v - hf.f);
}

// Gram partials: MP[part][i*NV+j], part = mat*16 + rblk, rows [rblk*75, +75).
// Deterministic (no atomics), 3 independent FMA chains.
__global__ __launch_bounds__(256) void kM(const float* __restrict__ Av,
    const float* __restrict__ Aa, const float* __restrict__ Ap, float* __restrict__ MP) {
  int bb = blockIdx.x % 144, part = blockIdx.x / 144;
  int idx = bb*256 + threadIdx.x;
  if (idx >= NV*NV) return;
  int i = idx / NV, j = idx - i*NV;
  const int mat = part >> 4;
  const float* __restrict__ A = (mat==0)?Av:((mat==1)?Aa:Ap);
  const int r0 = (part & 15) * 75;
  float a0=0.f, a1=0.f, a2=0.f;
  #pragma unroll 5
  for (int r=r0; r<r0+75; r+=3) {
    a0 = fmaf(A[(size_t)r*NV+i],     A[(size_t)r*NV+j],     a0);
    a1 = fmaf(A[(size_t)(r+1)*NV+i], A[(size_t)(r+1)*NV+j], a1);
    a2 = fmaf(A[(size_t)(r+2)*NV+i], A[(size_t)(r+2)*NV+j], a2);
  }
  MP[(size_t)part*NV*NV + idx] = (a0 + a1) + a2;
}

// sum Gram partials (fixed order) and swizzle into MFMA A-frags (bf16 hi/lo)
__global__ __launch_bounds__(256) void kS(const float* __restrict__ MP,
    unsigned short* __restrict__ Mh, unsigned short* __restrict__ Ml) {
  int idx = blockIdx.x*256 + threadIdx.x;
  if (idx >= 12*6*512) return;
  int jj = idx&7, lane=(idx>>3)&63, kb=(idx>>9)%6, mb=(idx>>9)/6;
  int i = mb*16 + (lane&15), k = kb*32 + (lane>>4)*8 + jj;
  const size_t e = (size_t)i*NV + k;
  float v = 0.f;
  #pragma unroll
  for (int p=0;p<NPART;++p) v += MP[(size_t)p*NV*NV + e];
  unsigned short h,l; bsplit2(v, h, l);
  Mh[idx]=h; Ml[idx]=l;
}

// init: S0 = lamv+lama+lamp+cin [192][2048]; C0 = c0^T [192][2048];
// xh/xl = split(c0) [s][192]; QTinv frags
__global__ __launch_bounds__(256) void ki(const float* __restrict__ lam,
    const float* __restrict__ cin, const float* __restrict__ c0,
    const float* __restrict__ Qinv, float* __restrict__ S0, float* __restrict__ C0,
    unsigned short* __restrict__ xh, unsigned short* __restrict__ xl,
    unsigned short* __restrict__ QTh, unsigned short* __restrict__ QTl) {
  int idx = blockIdx.x*256 + threadIdx.x;
  if (idx < NV*B2) {
    int j = idx / B2, s = idx - j*B2;
    S0[idx] = lam[(size_t)s*576 + j] + lam[(size_t)s*576 + 192 + j]
            + lam[(size_t)s*576 + 384 + j] + cin[(size_t)s*NV + j];
    return;
  }
  idx -= NV*B2;
  if (idx < NV*B2) { int i = idx / B2, s = idx - i*B2; C0[idx] = c0[(size_t)s*NV + i]; return; }
  idx -= NV*B2;
  if (idx < NV*B2) {
    unsigned short h,l; bsplit2(c0[idx], h, l);   // same [s][192] linear layout
    xh[idx]=h; xl[idx]=l;
    return;
  }
  idx -= NV*B2;
  if (idx < 12*7*512) {
    int jj = idx&7, lane=(idx>>3)&63, kb=(idx>>9)%7, mb=(idx>>9)/7;
    int i = mb*16 + (lane&15), j = kb*32 + (lane>>4)*8 + jj;
    float v = (j < NTT) ? Qinv[(size_t)i*NTT + j] : 0.f;
    unsigned short h,l; bsplit2(v,h,l);
    QTh[idx]=h; QTl[idx]=l;
  }
}

// A operand swizzle (validated r2/r4/r6/r7/r8/r10)
__global__ __launch_bounds__(256) void kA(const float* __restrict__ Av,
    const float* __restrict__ Aa, const float* __restrict__ Ap,
    unsigned short* __restrict__ Ah, unsigned short* __restrict__ Al,
    unsigned short* __restrict__ Ath, unsigned short* __restrict__ Atl) {
  int idx = blockIdx.x*256 + threadIdx.x;
  const int HALF = 3*80*6*512;
  if (idx >= 2*HALF) return;
  if (idx < HALF) {
    int j = idx&7, lane=(idx>>3)&63, kb=(idx>>9)%6, rb=(idx>>9)/6%80, mat=idx/(80*6*512);
    int row = rb*16 + (lane&15), col = kb*32 + (lane>>4)*8 + j;
    const float* A = (mat==0)?Av:((mat==1)?Aa:Ap);
    float v = (row < 1200) ? A[(size_t)row*NV + col] : 0.f;
    unsigned short h,l; bsplit2(v,h,l); Ah[idx]=h; Al[idx]=l;
  } else {
    int oi = idx - HALF;
    int jj = oi&7, lane=(oi>>3)&63, kbr=(oi>>9)%40, cb=(oi>>9)/40%12, mat=oi/(12*40*512);
    int row = kbr*32 + (lane>>4)*8 + jj, col = cb*16 + (lane&15);
    const float* A = (mat==0)?Av:((mat==1)?Aa:Ap);
    float v = (row < 1200) ? A[(size_t)row*NV + col] : 0.f;
    unsigned short h,l; bsplit2(v,h,l); Ath[oi]=h; Atl[oi]=l;
  }
}

// ---- kP: per-tile solve. grid = 128, block = 512. (unchanged from r7/r8/r10) ----
__global__ __launch_bounds__(512) void kP(
    const float* __restrict__ Sin, float* __restrict__ Sout,
    const float* __restrict__ Cin, float* __restrict__ Cout,
    const float* __restrict__ beq,
    const float* __restrict__ dl, const float* __restrict__ sqP,
    unsigned short* __restrict__ xh, unsigned short* __restrict__ xl,
    const unsigned short* __restrict__ QTh, const unsigned short* __restrict__ QTl,
    const unsigned short* __restrict__ Mh, const unsigned short* __restrict__ Ml,
    float* __restrict__ tot, int upd)
{
  __shared__ unsigned short rhsH[16*KPAD], rhsL[16*KPAD];
  __shared__ float mxL[16*PMX];
  __shared__ float lamAcc[64];   // [0..47] dl-norm partials, [48..63] xdiff
  const int tid = threadIdx.x, wave = tid>>6, lane = tid&63;
  const int n = lane&15, q = lane>>4;
  const int tile0 = blockIdx.x*16, ts = tile0+n;

  if (tid<64) lamAcc[tid] = 0.f;

  s16x8 xfh[6], xfl[6];
  {
    const size_t xo = (size_t)ts*NV + q*8;
    #pragma unroll
    for (int kb=0;kb<6;++kb) {
      xfh[kb] = *(const s16x8*)(xh + xo + kb*32);
      xfl[kb] = *(const s16x8*)(xl + xo + kb*32);
    }
  }
  __syncthreads();
  // Mall * x
  #pragma unroll 1
  for (int mi=0;mi<2;++mi) {
    const int mb = wave + mi*8;
    if (mb>=12) break;
    f32x4 a0={0,0,0,0}, a1={0,0,0,0}, a2={0,0,0,0};
    #pragma unroll
    for (int kb=0;kb<6;++kb) {
      s16x8 mh = *(const s16x8*)(Mh + ((size_t)(mb*6+kb))*512 + lane*8);
      s16x8 ml = *(const s16x8*)(Ml + ((size_t)(mb*6+kb))*512 + lane*8);
      a0 = MFMA(mh, xfh[kb], a0);
      a1 = MFMA(mh, xfl[kb], a1);
      a2 = MFMA(ml, xfh[kb], a2);
    }
    #pragma unroll
    for (int r=0;r<4;++r) mxL[n*PMX + mb*16 + q*4 + r] = a0[r]+a1[r]+a2[r];
  }
  __syncthreads();
  // dl sums, S update, rhs build, lambda-norm partials
  {
    const int s = tid & 15, jg = tid >> 4;
    const int sg = tile0 + s;
    float l0=0.f, l1=0.f, l2=0.f;
    #pragma unroll 1
    for (int jp=0;jp<6;++jp) {
      const int j = jg + jp*32;
      float dm0=0.f, dm1=0.f, dm2=0.f;
      #pragma unroll
      for (int c=0;c<4;++c) {
        dm0 += dl[((size_t)c*576 + j)*B2 + sg];
        dm1 += dl[((size_t)c*576 + NV + j)*B2 + sg];
        dm2 += dl[((size_t)c*576 + 2*NV + j)*B2 + sg];
      }
      const float dsum = dm0+dm1+dm2;
      const float Sc = Sin[(size_t)j*B2 + sg];
      const float Sn = upd ? (Sc - dsum) : Sc;   // d=1: dl_0 is G-only, no lam update
      Sout[(size_t)j*B2 + sg] = Sn;
      const float rv = Sn + mxL[s*PMX + j] - dsum;   // = S_new + G
      unsigned short h,l; bsplit2(rv,h,l);
      rhsH[s*KPAD + j] = h; rhsL[s*KPAD + j] = l;
      l0 += dm0*dm0; l1 += dm1*dm1; l2 += dm2*dm2;
    }
    l0 += __shfl_xor(l0,16); l0 += __shfl_xor(l0,32);
    l1 += __shfl_xor(l1,16); l1 += __shfl_xor(l1,32);
    l2 += __shfl_xor(l2,16); l2 += __shfl_xor(l2,32);
    if (q==0 && upd) {
      atomicAdd(&lamAcc[n], l0);
      atomicAdd(&lamAcc[16+n], l1);
      atomicAdd(&lamAcc[32+n], l2);
    }
  }
  if (tid < 480) {
    const int je = tid>>4, sB = tid&15;
    unsigned short h,l; bsplit2(beq[(size_t)(tile0+sB)*30 + je], h, l);
    rhsH[sB*KPAD + NV + je] = h; rhsL[sB*KPAD + NV + je] = l;
  }
  if (tid < 160) {   // zero pad j = 222..231
    const int sB = tid&15, jt = NTT + (tid>>4);
    rhsH[sB*KPAD + jt] = 0; rhsL[sB*KPAD + jt] = 0;
  }
  __syncthreads();
  // Qinv MFMA -> primal
  s16x8 rfh[7], rfl[7];
  #pragma unroll
  for (int kb=0;kb<7;++kb) {
    rfh[kb] = *(const s16x8*)(rhsH + n*KPAD + kb*32 + q*8);
    rfl[kb] = *(const s16x8*)(rhsL + n*KPAD + kb*32 + q*8);
  }
  float xdl = 0.f;
  #pragma unroll 1
  for (int mi=0;mi<2;++mi) {
    const int mb = wave + mi*8;
    if (mb>=12) break;
    f32x4 a0={0,0,0,0}, a1={0,0,0,0}, a2={0,0,0,0};
    #pragma unroll
    for (int kb=0;kb<7;++kb) {
      s16x8 qh = *(const s16x8*)(QTh + ((size_t)(mb*7+kb))*512 + lane*8);
      s16x8 ql = *(const s16x8*)(QTl + ((size_t)(mb*7+kb))*512 + lane*8);
      a0 = MFMA(qh, rfh[kb], a0);
      a1 = MFMA(qh, rfl[kb], a1);
      a2 = MFMA(ql, rfh[kb], a2);
    }
    unsigned short xh4[4], xl4[4];
    #pragma unroll
    for (int r=0;r<4;++r) {
      const float xv = a0[r]+a1[r]+a2[r];
      const int i = mb*16 + q*4 + r;
      const float df = xv - Cin[(size_t)i*B2 + ts];
      xdl += df*df;
      Cout[(size_t)i*B2 + ts] = xv;
      bsplit2(xv, xh4[r], xl4[r]);
    }
    uint2 pk;
    pk.x = (unsigned)xh4[0] | ((unsigned)xh4[1]<<16);
    pk.y = (unsigned)xh4[2] | ((unsigned)xh4[3]<<16);
    *(uint2*)(xh + (size_t)ts*NV + mb*16 + q*4) = pk;
    pk.x = (unsigned)xl4[0] | ((unsigned)xl4[1]<<16);
    pk.y = (unsigned)xl4[2] | ((unsigned)xl4[3]<<16);
    *(uint2*)(xl + (size_t)ts*NV + mb*16 + q*4) = pk;
  }
  xdl += __shfl_xor(xdl,16); xdl += __shfl_xor(xdl,32);
  if (q==0) atomicAdd(&lamAcc[48+n], xdl);
  __syncthreads();
  // finalize tot: ||dl_{t-1}|| (upd) + res/sd_{t-1} (sqP; skipped at d=1) + xdiff_t
  if (tid < 16) {
    const int sg2 = tile0 + tid;
    float fp = sqrtf(lamAcc[tid]) + sqrtf(lamAcc[16+tid])
             + sqrtf(lamAcc[32+tid]) + sqrtf(lamAcc[48+tid]);
    float rp = 0.f;
    if (upd) {
      #pragma unroll
      for (int sl=0;sl<6;++sl) {
        float v = sqP[(size_t)sg2*8+sl] + sqP[16384+(size_t)sg2*8+sl]
                + sqP[2*16384+(size_t)sg2*8+sl] + sqP[3*16384+(size_t)sg2*8+sl];
        float nn = sqrtf(v);
        if (sl<3) rp += nn; else fp += nn;
      }
      tot[(size_t)sg2*2+0] += fp;
      tot[(size_t)sg2*2+1] += rp;
    } else {
      tot[(size_t)sg2*2+0] = fp;   // first iteration: initialize (ws is poisoned)
      tot[(size_t)sg2*2+1] = 0.f;
    }
  }
}

// ---- k2: A-streamer, MTILE=16, mat-split. grid = 1536
// (blockIdx = mat*512 + tile*4 + chunk, tile in [0,128)), block = 512,
// launch_bounds(512,4): 2 WGs/CU (4 waves/SIMD), ~95 regs -> no spill.
template<int FIRST>
__global__ __launch_bounds__(512, 4) void k2(
    const unsigned short* __restrict__ Ah, const unsigned short* __restrict__ Al,
    const unsigned short* __restrict__ Ath, const unsigned short* __restrict__ Atl,
    const unsigned short* __restrict__ xh, const unsigned short* __restrict__ xl,
    __half* __restrict__ uW, float* __restrict__ dl, float* __restrict__ sqP)
{
  __shared__ unsigned short rsh[16*PR], rsl[16*PR];
  __shared__ float sqAcc[32];   // [res/sd][sample 16] for this mat
  const int tid = threadIdx.x, wave = tid>>6, lane = tid&63;
  const int n = lane&15, q = lane>>4;
  const int mat = blockIdx.x >> 9;
  const int rest = blockIdx.x & 511;
  const int tile = rest >> 2, chunk = rest & 3;
  const int tile0 = tile*16;
  const float b = (mat==0)?0.8f:((mat==1)?1.8f:3.14159265358979f);

  if (tid < 32) sqAcc[tid] = 0.f;

  // x B-frags (one 16-sample group)
  s16x8 xfh[6], xfl[6];
  {
    const size_t xo = (size_t)(tile0 + n)*NV + q*8;
    #pragma unroll
    for (int kb=0;kb<6;++kb) {
      xfh[kb] = *(const s16x8*)(xh + xo + kb*32);
      xfl[kb] = *(const s16x8*)(xl + xo + kb*32);
    }
  }
  __syncthreads();

  float rsq = 0.f, ssq = 0.f;
  // fwd: v = A x, rs/u
  #pragma unroll 1
  for (int ri=0; ri<3; ++ri) {
    const int rbl = wave + ri*8;
    if (rbl >= 20) break;
    const int rb = chunk*20 + rbl;
    f32x4 a0={0,0,0,0}, a1={0,0,0,0}, a2={0,0,0,0};
    const size_t ab = ((size_t)(mat*80+rb)*6)*512 + (size_t)lane*8;
    #pragma unroll
    for (int kb=0;kb<6;++kb) {
      s16x8 ah = *(const s16x8*)(Ah + ab + (size_t)kb*512);
      s16x8 al = *(const s16x8*)(Al + ab + (size_t)kb*512);
      a0 = MFMA(ah, xfh[kb], a0);
      a1 = MFMA(ah, xfl[kb], a1);
      a2 = MFMA(al, xfh[kb], a2);
    }
    unsigned short rh4[4], rl4[4];
    #pragma unroll
    for (int r4i=0;r4i<4;++r4i) {
      const float v = a0[r4i]+a1[r4i]+a2[r4i];
      const float rs = fmaxf(v-b, 0.f);
      const int r = rb*16 + q*4 + r4i;
      if (r < 1200) {
        const float u = fminf(v, b);
        const size_t ui = ((size_t)mat*1200 + r)*B2 + tile0 + n;
        if (!FIRST) {
          const float sd = u - __half2float(uW[ui]);
          ssq += sd*sd; rsq += rs*rs;
        }
        uW[ui] = __float2half(u);
      }
      bsplit2(rs, rh4[r4i], rl4[r4i]);
    }
    const int lo = n*PR + rbl*16 + q*4;
    uint2 pk;
    pk.x = (unsigned)rh4[0] | ((unsigned)rh4[1]<<16);
    pk.y = (unsigned)rh4[2] | ((unsigned)rh4[3]<<16);
    *(uint2*)(rsh + lo) = pk;
    pk.x = (unsigned)rl4[0] | ((unsigned)rl4[1]<<16);
    pk.y = (unsigned)rl4[2] | ((unsigned)rl4[3]<<16);
    *(uint2*)(rsl + lo) = pk;
  }
  if (!FIRST) {
    rsq += __shfl_xor(rsq,16); rsq += __shfl_xor(rsq,32);
    ssq += __shfl_xor(ssq,16); ssq += __shfl_xor(ssq,32);
    if (q==0) {
      atomicAdd(&sqAcc[n], rsq);
      atomicAdd(&sqAcc[16+n], ssq);
    }
  }
  __syncthreads();
  // transpose: dl = A^T rs
  #pragma unroll 1
  for (int ci=0; ci<2; ++ci) {
    const int cb = wave + ci*8;
    if (cb >= 12) break;
    f32x4 a0={0,0,0,0}, a1={0,0,0,0}, a2={0,0,0,0};
    const size_t tb = ((size_t)((mat*12+cb)*40) + chunk*10)*512 + (size_t)lane*8;
    const int lb = n*PR + q*8;
    #pragma unroll 2
    for (int kk=0;kk<10;++kk) {
      s16x8 th = *(const s16x8*)(Ath + tb + (size_t)kk*512);
      s16x8 tl = *(const s16x8*)(Atl + tb + (size_t)kk*512);
      s16x8 rh = *(const s16x8*)(rsh + lb + kk*32);
      s16x8 rl = *(const s16x8*)(rsl + lb + kk*32);
      a0 = MFMA(th, rh, a0);
      a1 = MFMA(th, rl, a1);
      a2 = MFMA(tl, rh, a2);
    }
    #pragma unroll
    for (int r4i=0;r4i<4;++r4i)
      dl[((size_t)chunk*576 + mat*NV + cb*16 + q*4 + r4i)*B2 + tile0 + n]
        = a0[r4i]+a1[r4i]+a2[r4i];
  }
  __syncthreads();
  if (!FIRST && tid<32) {
    int s = tid & 15, half = tid >> 4;
    int sl = half ? (3 + mat) : mat;
    sqP[(size_t)chunk*16384 + (size_t)(tile0+s)*8 + sl] = sqAcc[half*16 + s];
  }
}

// finalize iteration-15 norms + outputs
__global__ __launch_bounds__(256) void k3(const float* __restrict__ dl,
    const float* __restrict__ sqP, const float* __restrict__ Cfin,
    const float* __restrict__ tot, float* __restrict__ out)
{
  __shared__ float sqL[8][4];
  const int tid = threadIdx.x;
  const int sb = blockIdx.x*8;
  if (tid<32) ((float*)sqL)[tid]=0.f;
  __syncthreads();
  for (int idx=tid; idx<8*576; idx+=256) {
    int s = idx&7, e = idx>>3;
    float v = 0.f;
    #pragma unroll
    for (int c=0;c<4;++c) v += dl[((size_t)c*576 + e)*B2 + sb + s];
    atomicAdd(&sqL[s][e/NV], v*v);
  }
  for (int idx=tid; idx<8*NV; idx+=256) {
    int s = idx/NV, i = idx - s*NV;
    out[(size_t)(sb+s)*NV + i] = Cfin[(size_t)i*B2 + sb + s];
  }
  __syncthreads();
  if (tid<8) {
    int s = tid, sg = sb+s;
    float fp = sqrtf(sqL[s][0]) + sqrtf(sqL[s][1]) + sqrtf(sqL[s][2]);
    float rp = 0.f;
    #pragma unroll
    for (int sl=0;sl<6;++sl) {
      float v = sqP[(size_t)sg*8+sl] + sqP[16384+(size_t)sg*8+sl]
              + sqP[2*16384+(size_t)sg*8+sl] + sqP[3*16384+(size_t)sg*8+sl];
      float nn = sqrtf(v);
      if (sl<3) rp += nn; else fp += nn;
    }
    fp += tot[(size_t)sg*2+0];
    rp += tot[(size_t)sg*2+1];
    out[(size_t)B2*NV + sg] = fp * (1.f/15.f);
    out[(size_t)B2*NV + B2 + sg] = rp * (1.f/15.f);
  }
}

extern "C" void kernel_launch(void* const* d_in, const int* in_sizes, int n_in,
                              void* d_out, int out_size, void* d_ws, size_t ws_size,
                              hipStream_t stream) {
  const float* lamda = (const float*)d_in[0];
  const float* cin   = (const float*)d_in[1];
  const float* c0    = (const float*)d_in[2];
  const float* beq   = (const float*)d_in[3];
  const float* Av    = (const float*)d_in[4];
  const float* Aa    = (const float*)d_in[5];
  const float* Ap    = (const float*)d_in[6];
  const float* Qinv  = (const float*)d_in[7];
  if (ws_size < (size_t)WS_FLOATS * sizeof(float)) return;

  float* ws = (float*)d_ws;
  float* S[2]  = { ws + O_S0, ws + O_S1 };
  float* C[2]  = { ws + O_C0, ws + O_C1 };
  __half* uW   = (__half*)(ws + O_U);
  float* dl    = ws + O_DL;
  float* sqP   = ws + O_SQP;
  float* tot   = ws + O_TOT;
  unsigned short* xh  = (unsigned short*)(ws + O_XH);
  unsigned short* xl  = (unsigned short*)(ws + O_XL);
  unsigned short* Ah  = (unsigned short*)(ws + O_AH);
  unsigned short* Al  = (unsigned short*)(ws + O_AL);
  unsigned short* Ath = (unsigned short*)(ws + O_ATH);
  unsigned short* Atl = (unsigned short*)(ws + O_ATL);
  unsigned short* QTh = (unsigned short*)(ws + O_QTH);
  unsigned short* QTl = (unsigned short*)(ws + O_QTL);
  unsigned short* Mh  = (unsigned short*)(ws + O_MH);
  unsigned short* Ml  = (unsigned short*)(ws + O_ML2);
  float* MP = ws + O_MP;
  float* out = (float*)d_out;

  kM<<<NPART*144, 256, 0, stream>>>(Av, Aa, Ap, MP);
  kS<<<144, 256, 0, stream>>>(MP, Mh, Ml);
  ki<<<(3*NV*B2 + 12*7*512 + 255)/256, 256, 0, stream>>>(lamda, cin, c0, Qinv,
      S[0], C[0], xh, xl, QTh, QTl);
  kA<<<(2*3*80*6*512 + 255)/256, 256, 0, stream>>>(Av, Aa, Ap, Ah, Al, Ath, Atl);

  // prime: u_0 and dl_0 = A^T relu(A c0 - b) from x = c0
  k2<1><<<1536, 512, 0, stream>>>(Ah, Al, Ath, Atl, xh, xl, uW, dl, sqP);
  for (int d = 1; d <= 15; ++d) {
    kP<<<128, 512, 0, stream>>>(S[(d+1)&1], S[d&1], C[(d+1)&1], C[d&1], beq,
        dl, sqP, xh, xl, QTh, QTl, Mh, Ml, tot, (d>=2)?1:0);
    k2<0><<<1536, 512, 0, stream>>>(Ah, Al, Ath, Atl, xh, xl, uW, dl, sqP);
  }
  k3<<<256, 256, 0, stream>>>(dl, sqP, C[1], tot, out);
}

// Round 12
// 1012.182 us; speedup vs baseline: 1.5501x; 1.3438x over previous
//
#include <hip/hip_runtime.h>
#include <hip/hip_fp16.h>

// MLPProjectionFilter round 12 = r10/r11 hybrid: k2 with MTILE=32 (low L2
// traffic, 377 MB/dispatch) AND 12 waves/CU (3 WGs of 256 thr, grid 768,
// launch_bounds(256,3) -> VGPR cap 170). Dual x-frags cost 96 VGPRs; the 3
// split-bf16 products per kb now accumulate into ONE chained f32x4 per group
// (saves 32 regs, fixed order -> deterministic). r11 proved occupancy rises
// when true reg use fits the cap; r8 proved traffic halves with MTILE=32.
// Per iter: kP (per-tile: dl-sum, S/lambda, G=Mall*x-dlsum, rhs, Qinv MFMA,
// norms) then k2 (A-stream: v=Ax fwd + dl=A^T rs transpose, split-bf16 MFMA).

typedef short s16x8 __attribute__((ext_vector_type(8)));
typedef float f32x4 __attribute__((ext_vector_type(4)));
#define MFMA(a,b,c) __builtin_amdgcn_mfma_f32_16x16x32_bf16(a,b,c,0,0,0)

#define B2 2048
#define NV 192
#define NTT 222
#define KPAD 232
#define PR 328        // k2 rs LDS pitch (ushort), 320 rows/chunk + pad
#define PMX 200       // kP mxL pitch (f32)
#define NPART 48      // Gram partials

// ---- ws layout (float offsets) ----
#define O_S0  0u
#define O_S1  393216u
#define O_C0  786432u
#define O_C1  1179648u
#define O_U   1572864u     // __half[3*1200*2048] = 3,686,400 fl
#define O_DL  5259264u     // f32 [4][576][2048] = 4,718,592
#define O_SQP 9977856u     // f32 [4][2048][8] = 65,536
#define O_TOT 10043392u    // f32 [2048][2] = 4,096
#define O_XH  10047488u    // ushort[2048*192] = 196,608 fl
#define O_XL  10244096u
#define O_AH  10440704u    // ushort[3*80*6*512] = 368,640 fl each
#define O_AL  10809344u
#define O_ATH 11177984u
#define O_ATL 11546624u
#define O_QTH 11915264u    // ushort[12*7*512] = 21,504 fl
#define O_QTL 11936768u
#define O_MH  11958272u    // ushort[12*6*512] = 18,432 fl
#define O_ML2 11976704u
#define O_MP  11995136u    // f32 [48][192*192] Gram partials = 1,769,472
#define WS_FLOATS 13764608u  // 55.1 MB

__device__ inline unsigned short bh16(float v){
  union{float f; unsigned u;} a; a.f=v;
  return (unsigned short)((a.u + 0x7FFFu + ((a.u>>16)&1u))>>16);
}
__device__ inline void bsplit2(float v, unsigned short& h, unsigned short& l){
  h = bh16(v);
  union{unsigned u; float f;} hf; hf.u = ((unsigned)h)<<16;
  l = bh16(v - hf.f);
}

// Gram partials: MP[part][i*NV+j], part = mat*16 + rblk, rows [rblk*75, +75).
// Deterministic (no atomics), 3 independent FMA chains.
__global__ __launch_bounds__(256) void kM(const float* __restrict__ Av,
    const float* __restrict__ Aa, const float* __restrict__ Ap, float* __restrict__ MP) {
  int bb = blockIdx.x % 144, part = blockIdx.x / 144;
  int idx = bb*256 + threadIdx.x;
  if (idx >= NV*NV) return;
  int i = idx / NV, j = idx - i*NV;
  const int mat = part >> 4;
  const float* __restrict__ A = (mat==0)?Av:((mat==1)?Aa:Ap);
  const int r0 = (part & 15) * 75;
  float a0=0.f, a1=0.f, a2=0.f;
  #pragma unroll 5
  for (int r=r0; r<r0+75; r+=3) {
    a0 = fmaf(A[(size_t)r*NV+i],     A[(size_t)r*NV+j],     a0);
    a1 = fmaf(A[(size_t)(r+1)*NV+i], A[(size_t)(r+1)*NV+j], a1);
    a2 = fmaf(A[(size_t)(r+2)*NV+i], A[(size_t)(r+2)*NV+j], a2);
  }
  MP[(size_t)part*NV*NV + idx] = (a0 + a1) + a2;
}

// sum Gram partials (fixed order) and swizzle into MFMA A-frags (bf16 hi/lo)
__global__ __launch_bounds__(256) void kS(const float* __restrict__ MP,
    unsigned short* __restrict__ Mh, unsigned short* __restrict__ Ml) {
  int idx = blockIdx.x*256 + threadIdx.x;
  if (idx >= 12*6*512) return;
  int jj = idx&7, lane=(idx>>3)&63, kb=(idx>>9)%6, mb=(idx>>9)/6;
  int i = mb*16 + (lane&15), k = kb*32 + (lane>>4)*8 + jj;
  const size_t e = (size_t)i*NV + k;
  float v = 0.f;
  #pragma unroll
  for (int p=0;p<NPART;++p) v += MP[(size_t)p*NV*NV + e];
  unsigned short h,l; bsplit2(v, h, l);
  Mh[idx]=h; Ml[idx]=l;
}

// init: S0 = lamv+lama+lamp+cin [192][2048]; C0 = c0^T [192][2048];
// xh/xl = split(c0) [s][192]; QTinv frags
__global__ __launch_bounds__(256) void ki(const float* __restrict__ lam,
    const float* __restrict__ cin, const float* __restrict__ c0,
    const float* __restrict__ Qinv, float* __restrict__ S0, float* __restrict__ C0,
    unsigned short* __restrict__ xh, unsigned short* __restrict__ xl,
    unsigned short* __restrict__ QTh, unsigned short* __restrict__ QTl) {
  int idx = blockIdx.x*256 + threadIdx.x;
  if (idx < NV*B2) {
    int j = idx / B2, s = idx - j*B2;
    S0[idx] = lam[(size_t)s*576 + j] + lam[(size_t)s*576 + 192 + j]
            + lam[(size_t)s*576 + 384 + j] + cin[(size_t)s*NV + j];
    return;
  }
  idx -= NV*B2;
  if (idx < NV*B2) { int i = idx / B2, s = idx - i*B2; C0[idx] = c0[(size_t)s*NV + i]; return; }
  idx -= NV*B2;
  if (idx < NV*B2) {
    unsigned short h,l; bsplit2(c0[idx], h, l);   // same [s][192] linear layout
    xh[idx]=h; xl[idx]=l;
    return;
  }
  idx -= NV*B2;
  if (idx < 12*7*512) {
    int jj = idx&7, lane=(idx>>3)&63, kb=(idx>>9)%7, mb=(idx>>9)/7;
    int i = mb*16 + (lane&15), j = kb*32 + (lane>>4)*8 + jj;
    float v = (j < NTT) ? Qinv[(size_t)i*NTT + j] : 0.f;
    unsigned short h,l; bsplit2(v,h,l);
    QTh[idx]=h; QTl[idx]=l;
  }
}

// A operand swizzle (validated r2/r4/r6/r7/r8/r10/r11)
__global__ __launch_bounds__(256) void kA(const float* __restrict__ Av,
    const float* __restrict__ Aa, const float* __restrict__ Ap,
    unsigned short* __restrict__ Ah, unsigned short* __restrict__ Al,
    unsigned short* __restrict__ Ath, unsigned short* __restrict__ Atl) {
  int idx = blockIdx.x*256 + threadIdx.x;
  const int HALF = 3*80*6*512;
  if (idx >= 2*HALF) return;
  if (idx < HALF) {
    int j = idx&7, lane=(idx>>3)&63, kb=(idx>>9)%6, rb=(idx>>9)/6%80, mat=idx/(80*6*512);
    int row = rb*16 + (lane&15), col = kb*32 + (lane>>4)*8 + j;
    const float* A = (mat==0)?Av:((mat==1)?Aa:Ap);
    float v = (row < 1200) ? A[(size_t)row*NV + col] : 0.f;
    unsigned short h,l; bsplit2(v,h,l); Ah[idx]=h; Al[idx]=l;
  } else {
    int oi = idx - HALF;
    int jj = oi&7, lane=(oi>>3)&63, kbr=(oi>>9)%40, cb=(oi>>9)/40%12, mat=oi/(12*40*512);
    int row = kbr*32 + (lane>>4)*8 + jj, col = cb*16 + (lane&15);
    const float* A = (mat==0)?Av:((mat==1)?Aa:Ap);
    float v = (row < 1200) ? A[(size_t)row*NV + col] : 0.f;
    unsigned short h,l; bsplit2(v,h,l); Ath[oi]=h; Atl[oi]=l;
  }
}

// ---- kP: per-tile solve. grid = 128, block = 512. (unchanged, validated) ----
__global__ __launch_bounds__(512) void kP(
    const float* __restrict__ Sin, float* __restrict__ Sout,
    const float* __restrict__ Cin, float* __restrict__ Cout,
    const float* __restrict__ beq,
    const float* __restrict__ dl, const float* __restrict__ sqP,
    unsigned short* __restrict__ xh, unsigned short* __restrict__ xl,
    const unsigned short* __restrict__ QTh, const unsigned short* __restrict__ QTl,
    const unsigned short* __restrict__ Mh, const unsigned short* __restrict__ Ml,
    float* __restrict__ tot, int upd)
{
  __shared__ unsigned short rhsH[16*KPAD], rhsL[16*KPAD];
  __shared__ float mxL[16*PMX];
  __shared__ float lamAcc[64];   // [0..47] dl-norm partials, [48..63] xdiff
  const int tid = threadIdx.x, wave = tid>>6, lane = tid&63;
  const int n = lane&15, q = lane>>4;
  const int tile0 = blockIdx.x*16, ts = tile0+n;

  if (tid<64) lamAcc[tid] = 0.f;

  s16x8 xfh[6], xfl[6];
  {
    const size_t xo = (size_t)ts*NV + q*8;
    #pragma unroll
    for (int kb=0;kb<6;++kb) {
      xfh[kb] = *(const s16x8*)(xh + xo + kb*32);
      xfl[kb] = *(const s16x8*)(xl + xo + kb*32);
    }
  }
  __syncthreads();
  // Mall * x
  #pragma unroll 1
  for (int mi=0;mi<2;++mi) {
    const int mb = wave + mi*8;
    if (mb>=12) break;
    f32x4 a0={0,0,0,0}, a1={0,0,0,0}, a2={0,0,0,0};
    #pragma unroll
    for (int kb=0;kb<6;++kb) {
      s16x8 mh = *(const s16x8*)(Mh + ((size_t)(mb*6+kb))*512 + lane*8);
      s16x8 ml = *(const s16x8*)(Ml + ((size_t)(mb*6+kb))*512 + lane*8);
      a0 = MFMA(mh, xfh[kb], a0);
      a1 = MFMA(mh, xfl[kb], a1);
      a2 = MFMA(ml, xfh[kb], a2);
    }
    #pragma unroll
    for (int r=0;r<4;++r) mxL[n*PMX + mb*16 + q*4 + r] = a0[r]+a1[r]+a2[r];
  }
  __syncthreads();
  // dl sums, S update, rhs build, lambda-norm partials
  {
    const int s = tid & 15, jg = tid >> 4;
    const int sg = tile0 + s;
    float l0=0.f, l1=0.f, l2=0.f;
    #pragma unroll 1
    for (int jp=0;jp<6;++jp) {
      const int j = jg + jp*32;
      float dm0=0.f, dm1=0.f, dm2=0.f;
      #pragma unroll
      for (int c=0;c<4;++c) {
        dm0 += dl[((size_t)c*576 + j)*B2 + sg];
        dm1 += dl[((size_t)c*576 + NV + j)*B2 + sg];
        dm2 += dl[((size_t)c*576 + 2*NV + j)*B2 + sg];
      }
      const float dsum = dm0+dm1+dm2;
      const float Sc = Sin[(size_t)j*B2 + sg];
      const float Sn = upd ? (Sc - dsum) : Sc;   // d=1: dl_0 is G-only, no lam update
      Sout[(size_t)j*B2 + sg] = Sn;
      const float rv = Sn + mxL[s*PMX + j] - dsum;   // = S_new + G
      unsigned short h,l; bsplit2(rv,h,l);
      rhsH[s*KPAD + j] = h; rhsL[s*KPAD + j] = l;
      l0 += dm0*dm0; l1 += dm1*dm1; l2 += dm2*dm2;
    }
    l0 += __shfl_xor(l0,16); l0 += __shfl_xor(l0,32);
    l1 += __shfl_xor(l1,16); l1 += __shfl_xor(l1,32);
    l2 += __shfl_xor(l2,16); l2 += __shfl_xor(l2,32);
    if (q==0 && upd) {
      atomicAdd(&lamAcc[n], l0);
      atomicAdd(&lamAcc[16+n], l1);
      atomicAdd(&lamAcc[32+n], l2);
    }
  }
  if (tid < 480) {
    const int je = tid>>4, sB = tid&15;
    unsigned short h,l; bsplit2(beq[(size_t)(tile0+sB)*30 + je], h, l);
    rhsH[sB*KPAD + NV + je] = h; rhsL[sB*KPAD + NV + je] = l;
  }
  if (tid < 160) {   // zero pad j = 222..231
    const int sB = tid&15, jt = NTT + (tid>>4);
    rhsH[sB*KPAD + jt] = 0; rhsL[sB*KPAD + jt] = 0;
  }
  __syncthreads();
  // Qinv MFMA -> primal
  s16x8 rfh[7], rfl[7];
  #pragma unroll
  for (int kb=0;kb<7;++kb) {
    rfh[kb] = *(const s16x8*)(rhsH + n*KPAD + kb*32 + q*8);
    rfl[kb] = *(const s16x8*)(rhsL + n*KPAD + kb*32 + q*8);
  }
  float xdl = 0.f;
  #pragma unroll 1
  for (int mi=0;mi<2;++mi) {
    const int mb = wave + mi*8;
    if (mb>=12) break;
    f32x4 a0={0,0,0,0}, a1={0,0,0,0}, a2={0,0,0,0};
    #pragma unroll
    for (int kb=0;kb<7;++kb) {
      s16x8 qh = *(const s16x8*)(QTh + ((size_t)(mb*7+kb))*512 + lane*8);
      s16x8 ql = *(const s16x8*)(QTl + ((size_t)(mb*7+kb))*512 + lane*8);
      a0 = MFMA(qh, rfh[kb], a0);
      a1 = MFMA(qh, rfl[kb], a1);
      a2 = MFMA(ql, rfh[kb], a2);
    }
    unsigned short xh4[4], xl4[4];
    #pragma unroll
    for (int r=0;r<4;++r) {
      const float xv = a0[r]+a1[r]+a2[r];
      const int i = mb*16 + q*4 + r;
      const float df = xv - Cin[(size_t)i*B2 + ts];
      xdl += df*df;
      Cout[(size_t)i*B2 + ts] = xv;
      bsplit2(xv, xh4[r], xl4[r]);
    }
    uint2 pk;
    pk.x = (unsigned)xh4[0] | ((unsigned)xh4[1]<<16);
    pk.y = (unsigned)xh4[2] | ((unsigned)xh4[3]<<16);
    *(uint2*)(xh + (size_t)ts*NV + mb*16 + q*4) = pk;
    pk.x = (unsigned)xl4[0] | ((unsigned)xl4[1]<<16);
    pk.y = (unsigned)xl4[2] | ((unsigned)xl4[3]<<16);
    *(uint2*)(xl + (size_t)ts*NV + mb*16 + q*4) = pk;
  }
  xdl += __shfl_xor(xdl,16); xdl += __shfl_xor(xdl,32);
  if (q==0) atomicAdd(&lamAcc[48+n], xdl);
  __syncthreads();
  // finalize tot: ||dl_{t-1}|| (upd) + res/sd_{t-1} (sqP; skipped at d=1) + xdiff_t
  if (tid < 16) {
    const int sg2 = tile0 + tid;
    float fp = sqrtf(lamAcc[tid]) + sqrtf(lamAcc[16+tid])
             + sqrtf(lamAcc[32+tid]) + sqrtf(lamAcc[48+tid]);
    float rp = 0.f;
    if (upd) {
      #pragma unroll
      for (int sl=0;sl<6;++sl) {
        float v = sqP[(size_t)sg2*8+sl] + sqP[16384+(size_t)sg2*8+sl]
                + sqP[2*16384+(size_t)sg2*8+sl] + sqP[3*16384+(size_t)sg2*8+sl];
        float nn = sqrtf(v);
        if (sl<3) rp += nn; else fp += nn;
      }
      tot[(size_t)sg2*2+0] += fp;
      tot[(size_t)sg2*2+1] += rp;
    } else {
      tot[(size_t)sg2*2+0] = fp;   // first iteration: initialize (ws is poisoned)
      tot[(size_t)sg2*2+1] = 0.f;
    }
  }
}

// ---- k2: A-streamer, MTILE=32, mat-split, block=256, 3 WGs/CU.
// grid = 768 (blockIdx = mat*256 + tile*4 + chunk, tile in [0,64)).
// Single chained f32x4 accumulator per sample group (fixed order, deterministic).
template<int FIRST>
__global__ __launch_bounds__(256, 3) void k2(
    const unsigned short* __restrict__ Ah, const unsigned short* __restrict__ Al,
    const unsigned short* __restrict__ Ath, const unsigned short* __restrict__ Atl,
    const unsigned short* __restrict__ xh, const unsigned short* __restrict__ xl,
    __half* __restrict__ uW, float* __restrict__ dl, float* __restrict__ sqP)
{
  __shared__ unsigned short rsh[32*PR], rsl[32*PR];
  __shared__ float sqAcc[64];   // [res/sd][sample 32] for this mat
  const int tid = threadIdx.x, wave = tid>>6, lane = tid&63;   // wave 0..3
  const int n = lane&15, q = lane>>4;
  const int mat = blockIdx.x >> 8;
  const int rest = blockIdx.x & 255;
  const int tile = rest >> 2, chunk = rest & 3;
  const int tile0 = tile*32;
  const float b = (mat==0)?0.8f:((mat==1)?1.8f:3.14159265358979f);

  if (tid < 64) sqAcc[tid] = 0.f;

  // x B-frags for both 16-sample groups
  s16x8 xfh[2][6], xfl[2][6];
  #pragma unroll
  for (int g=0;g<2;++g) {
    const size_t xo = (size_t)(tile0 + g*16 + n)*NV + q*8;
    #pragma unroll
    for (int kb=0;kb<6;++kb) {
      xfh[g][kb] = *(const s16x8*)(xh + xo + kb*32);
      xfl[g][kb] = *(const s16x8*)(xl + xo + kb*32);
    }
  }
  __syncthreads();

  float rsq[2]={0.f,0.f}, ssq[2]={0.f,0.f};
  // fwd: v = A x, rs/u — A-frags loaded once, used for both groups
  #pragma unroll 1
  for (int ri=0; ri<5; ++ri) {
    const int rbl = wave + ri*4;              // 0..19
    const int rb = chunk*20 + rbl;
    f32x4 acc[2];
    acc[0] = (f32x4){0.f,0.f,0.f,0.f};
    acc[1] = (f32x4){0.f,0.f,0.f,0.f};
    const size_t ab = ((size_t)(mat*80+rb)*6)*512 + (size_t)lane*8;
    #pragma unroll
    for (int kb=0;kb<6;++kb) {
      s16x8 ah = *(const s16x8*)(Ah + ab + (size_t)kb*512);
      s16x8 al = *(const s16x8*)(Al + ab + (size_t)kb*512);
      #pragma unroll
      for (int g=0;g<2;++g) {
        acc[g] = MFMA(al, xfh[g][kb], acc[g]);
        acc[g] = MFMA(ah, xfl[g][kb], acc[g]);
        acc[g] = MFMA(ah, xfh[g][kb], acc[g]);
      }
    }
    #pragma unroll
    for (int g=0;g<2;++g) {
      unsigned short rh4[4], rl4[4];
      #pragma unroll
      for (int r4i=0;r4i<4;++r4i) {
        const float v = acc[g][r4i];
        const float rs = fmaxf(v-b, 0.f);
        const int r = rb*16 + q*4 + r4i;
        if (r < 1200) {
          const float u = fminf(v, b);
          const size_t ui = ((size_t)mat*1200 + r)*B2 + tile0 + g*16 + n;
          if (!FIRST) {
            const float sd = u - __half2float(uW[ui]);
            ssq[g] += sd*sd; rsq[g] += rs*rs;
          }
          uW[ui] = __float2half(u);
        }
        bsplit2(rs, rh4[r4i], rl4[r4i]);
      }
      const int lo = (g*16+n)*PR + rbl*16 + q*4;
      uint2 pk;
      pk.x = (unsigned)rh4[0] | ((unsigned)rh4[1]<<16);
      pk.y = (unsigned)rh4[2] | ((unsigned)rh4[3]<<16);
      *(uint2*)(rsh + lo) = pk;
      pk.x = (unsigned)rl4[0] | ((unsigned)rl4[1]<<16);
      pk.y = (unsigned)rl4[2] | ((unsigned)rl4[3]<<16);
      *(uint2*)(rsl + lo) = pk;
    }
  }
  if (!FIRST) {
    #pragma unroll
    for (int g=0;g<2;++g) {
      float r1 = rsq[g], s1 = ssq[g];
      r1 += __shfl_xor(r1,16); r1 += __shfl_xor(r1,32);
      s1 += __shfl_xor(s1,16); s1 += __shfl_xor(s1,32);
      if (q==0) {
        atomicAdd(&sqAcc[g*16 + n], r1);
        atomicAdd(&sqAcc[32 + g*16 + n], s1);
      }
    }
  }
  __syncthreads();
  // transpose: dl = A^T rs (A-frags reused across both groups)
  #pragma unroll 1
  for (int ci=0; ci<3; ++ci) {
    const int cb = wave + ci*4;               // 0..11
    f32x4 dacc[2];
    dacc[0] = (f32x4){0.f,0.f,0.f,0.f};
    dacc[1] = (f32x4){0.f,0.f,0.f,0.f};
    const size_t tb = ((size_t)((mat*12+cb)*40) + chunk*10)*512 + (size_t)lane*8;
    #pragma unroll 2
    for (int kk=0;kk<10;++kk) {
      s16x8 th = *(const s16x8*)(Ath + tb + (size_t)kk*512);
      s16x8 tl = *(const s16x8*)(Atl + tb + (size_t)kk*512);
      #pragma unroll
      for (int g=0;g<2;++g) {
        const int lb = (g*16+n)*PR + q*8 + kk*32;
        s16x8 rh = *(const s16x8*)(rsh + lb);
        s16x8 rl = *(const s16x8*)(rsl + lb);
        dacc[g] = MFMA(tl, rh, dacc[g]);
        dacc[g] = MFMA(th, rl, dacc[g]);
        dacc[g] = MFMA(th, rh, dacc[g]);
      }
    }
    #pragma unroll
    for (int g=0;g<2;++g)
      #pragma unroll
      for (int r4i=0;r4i<4;++r4i)
        dl[((size_t)chunk*576 + mat*NV + cb*16 + q*4 + r4i)*B2 + tile0 + g*16 + n]
          = dacc[g][r4i];
  }
  __syncthreads();
  if (!FIRST && tid<64) {
    int s = tid & 31, half = tid >> 5;
    int sl = half ? (3 + mat) : mat;
    sqP[(size_t)chunk*16384 + (size_t)(tile0+s)*8 + sl] = sqAcc[half*32 + s];
  }
}

// finalize iteration-15 norms + outputs
__global__ __launch_bounds__(256) void k3(const float* __restrict__ dl,
    const float* __restrict__ sqP, const float* __restrict__ Cfin,
    const float* __restrict__ tot, float* __restrict__ out)
{
  __shared__ float sqL[8][4];
  const int tid = threadIdx.x;
  const int sb = blockIdx.x*8;
  if (tid<32) ((float*)sqL)[tid]=0.f;
  __syncthreads();
  for (int idx=tid; idx<8*576; idx+=256) {
    int s = idx&7, e = idx>>3;
    float v = 0.f;
    #pragma unroll
    for (int c=0;c<4;++c) v += dl[((size_t)c*576 + e)*B2 + sb + s];
    atomicAdd(&sqL[s][e/NV], v*v);
  }
  for (int idx=tid; idx<8*NV; idx+=256) {
    int s = idx/NV, i = idx - s*NV;
    out[(size_t)(sb+s)*NV + i] = Cfin[(size_t)i*B2 + sb + s];
  }
  __syncthreads();
  if (tid<8) {
    int s = tid, sg = sb+s;
    float fp = sqrtf(sqL[s][0]) + sqrtf(sqL[s][1]) + sqrtf(sqL[s][2]);
    float rp = 0.f;
    #pragma unroll
    for (int sl=0;sl<6;++sl) {
      float v = sqP[(size_t)sg*8+sl] + sqP[16384+(size_t)sg*8+sl]
              + sqP[2*16384+(size_t)sg*8+sl] + sqP[3*16384+(size_t)sg*8+sl];
      float nn = sqrtf(v);
      if (sl<3) rp += nn; else fp += nn;
    }
    fp += tot[(size_t)sg*2+0];
    rp += tot[(size_t)sg*2+1];
    out[(size_t)B2*NV + sg] = fp * (1.f/15.f);
    out[(size_t)B2*NV + B2 + sg] = rp * (1.f/15.f);
  }
}

extern "C" void kernel_launch(void* const* d_in, const int* in_sizes, int n_in,
                              void* d_out, int out_size, void* d_ws, size_t ws_size,
                              hipStream_t stream) {
  const float* lamda = (const float*)d_in[0];
  const float* cin   = (const float*)d_in[1];
  const float* c0    = (const float*)d_in[2];
  const float* beq   = (const float*)d_in[3];
  const float* Av    = (const float*)d_in[4];
  const float* Aa    = (const float*)d_in[5];
  const float* Ap    = (const float*)d_in[6];
  const float* Qinv  = (const float*)d_in[7];
  if (ws_size < (size_t)WS_FLOATS * sizeof(float)) return;

  float* ws = (float*)d_ws;
  float* S[2]  = { ws + O_S0, ws + O_S1 };
  float* C[2]  = { ws + O_C0, ws + O_C1 };
  __half* uW   = (__half*)(ws + O_U);
  float* dl    = ws + O_DL;
  float* sqP   = ws + O_SQP;
  float* tot   = ws + O_TOT;
  unsigned short* xh  = (unsigned short*)(ws + O_XH);
  unsigned short* xl  = (unsigned short*)(ws + O_XL);
  unsigned short* Ah  = (unsigned short*)(ws + O_AH);
  unsigned short* Al  = (unsigned short*)(ws + O_AL);
  unsigned short* Ath = (unsigned short*)(ws + O_ATH);
  unsigned short* Atl = (unsigned short*)(ws + O_ATL);
  unsigned short* QTh = (unsigned short*)(ws + O_QTH);
  unsigned short* QTl = (unsigned short*)(ws + O_QTL);
  unsigned short* Mh  = (unsigned short*)(ws + O_MH);
  unsigned short* Ml  = (unsigned short*)(ws + O_ML2);
  float* MP = ws + O_MP;
  float* out = (float*)d_out;

  kM<<<NPART*144, 256, 0, stream>>>(Av, Aa, Ap, MP);
  kS<<<144, 256, 0, stream>>>(MP, Mh, Ml);
  ki<<<(3*NV*B2 + 12*7*512 + 255)/256, 256, 0, stream>>>(lamda, cin, c0, Qinv,
      S[0], C[0], xh, xl, QTh, QTl);
  kA<<<(2*3*80*6*512 + 255)/256, 256, 0, stream>>>(Av, Aa, Ap, Ah, Al, Ath, Atl);

  // prime: u_0 and dl_0 = A^T relu(A c0 - b) from x = c0
  k2<1><<<768, 256, 0, stream>>>(Ah, Al, Ath, Atl, xh, xl, uW, dl, sqP);
  for (int d = 1; d <= 15; ++d) {
    kP<<<128, 512, 0, stream>>>(S[(d+1)&1], S[d&1], C[(d+1)&1], C[d&1], beq,
        dl, sqP, xh, xl, QTh, QTl, Mh, Ml, tot, (d>=2)?1:0);
    k2<0><<<768, 256, 0, stream>>>(Ah, Al, Ath, Atl, xh, xl, uW, dl, sqP);
  }
  k3<<<256, 256, 0, stream>>>(dl, sqP, C[1], tot, out);
}